// Round 1
// baseline (8216.418 us; speedup 1.0000x reference)
//
#include <hip/hip_runtime.h>
#include <hip/hip_bf16.h>

// Problem constants
constexpr int NB = 4;        // batch
constexpr int CC = 128;      // channels
constexpr int HW = 65536;    // 256*256 pixels per (b, channel) plane
// windows: 32x32 = 1024 per batch, 8x8 = 64 px per window

__device__ __forceinline__ float from_st(float v) { return v; }
__device__ __forceinline__ float from_st(__hip_bfloat16 v) { return __bfloat162float(v); }
__device__ __forceinline__ void store_st(float* p, float v) { *p = v; }
__device__ __forceinline__ void store_st(__hip_bfloat16* p, float v) { *p = __float2bfloat16(v); }

// ---------------- Kernel 1: rolled 1x1 conv  qkv[g][b][c][h][w] (rolled space) ----------
template <typename ST>
__global__ __launch_bounds__(256) void k_qkv(const float* __restrict__ x,
                                             const float* __restrict__ wq,
                                             ST* __restrict__ qkv) {
  int id = blockIdx.x * 256 + threadIdx.x;     // (b, i, j)
  int b = id >> 16;
  int i = (id >> 8) & 255;
  int j = id & 255;
  int si = (i + 4) & 255, sj = (j + 4) & 255;  // roll(-4,-4): x_[i,j] = x[i+4, j+4]
  const float* xp = x + (((size_t)b * CC) << 16) + (si << 8) + sj;
  float xr[CC];
#pragma unroll
  for (int c = 0; c < CC; ++c) xr[c] = xp[(size_t)c << 16];
  for (int och = 0; och < 3 * CC; ++och) {
    const float* wrow = wq + och * CC;   // uniform -> s_load
    float acc = 0.f;
#pragma unroll
    for (int c = 0; c < CC; ++c) acc = fmaf(wrow[c], xr[c], acc);
    int g = och >> 7, cl = och & 127;
    store_st(&qkv[(((size_t)((g * NB + b) * CC + cl)) << 16) + (i << 8) + j], acc);
  }
}

// ------- dw-conv halo staging helper: stage 16 channels of a 10x10 halo --------
template <typename ST>
__device__ __forceinline__ void stage_halo(const ST* __restrict__ qkv, int g, int b,
                                           int cc, int ih0, int iw0, int t,
                                           float (*halo)[10][12]) {
  for (int idx = t; idx < 1600; idx += 256) {
    int ch = idx / 100, pos = idx - ch * 100;
    int r = pos / 10, cl = pos - r * 10;
    int ii = ih0 - 1 + r, jj = iw0 - 1 + cl;
    float v = 0.f;
    if ((unsigned)ii < 256u && (unsigned)jj < 256u)
      v = from_st(qkv[(((size_t)((g * NB + b) * CC + cc * 16 + ch)) << 16) + (ii << 8) + jj]);
    halo[ch][r][cl] = v;
  }
}

// ---------------- Kernel 2a: dw(q,k) + normalize + attn = relu(tau * Q^T K) -----------
template <typename ST>
__global__ __launch_bounds__(256) void k_attn(const ST* __restrict__ qkv,
                                              const float* __restrict__ wdw,
                                              const float* __restrict__ temp_p,
                                              float* __restrict__ attn_out) {
  __shared__ float q_s[64][136];
  __shared__ float k_s[64][136];
  __shared__ float halo[16][10][12];
  __shared__ float sumsq[2][64];
  __shared__ float pscale[64];

  int blk = blockIdx.x;              // b*1024 + n
  int b = blk >> 10, n = blk & 1023;
  int ih0 = (n >> 5) << 3, iw0 = (n & 31) << 3;   // window origin (rolled space)
  int t = threadIdx.x;
  if (t < 128) sumsq[t >> 6][t & 63] = 0.f;

  int ch_l = t & 15, pq = t >> 4;
#pragma unroll
  for (int g = 0; g < 2; ++g) {   // 0 = q, 1 = k
    float(*dst)[136] = (g == 0) ? q_s : k_s;
    for (int cc = 0; cc < 8; ++cc) {
      __syncthreads();
      stage_halo(qkv, g, b, cc, ih0, iw0, t, halo);
      __syncthreads();
      float wd[9];
#pragma unroll
      for (int kk = 0; kk < 9; ++kk) wd[kk] = wdw[(g * CC + cc * 16 + ch_l) * 9 + kk];
#pragma unroll
      for (int u = 0; u < 4; ++u) {
        int px = pq + (u << 4);
        int pr = px >> 3, pc = px & 7;
        float v = 0.f;
#pragma unroll
        for (int r = 0; r < 3; ++r)
#pragma unroll
          for (int s = 0; s < 3; ++s) v = fmaf(wd[r * 3 + s], halo[ch_l][pr + r][pc + s], v);
        dst[px][cc * 16 + ch_l] = v;
        float sq = v * v;                      // per-pixel sum of squares over channels
        sq += __shfl_xor(sq, 1);
        sq += __shfl_xor(sq, 2);
        sq += __shfl_xor(sq, 4);
        sq += __shfl_xor(sq, 8);
        if (ch_l == 0) sumsq[g][px] += sq;
      }
    }
  }
  __syncthreads();
  if (t < 64) {
    float nq = fmaxf(sqrtf(sumsq[0][t]), 1e-12f);
    float nk = fmaxf(sqrtf(sumsq[1][t]), 1e-12f);
    pscale[t] = temp_p[0] / (nq * nk);          // fold tau and both norms into q rows
  }
  __syncthreads();
  for (int idx = t; idx < 64 * 128; idx += 256) {
    int px = idx >> 7, c = idx & 127;
    q_s[px][c] *= pscale[px];
  }
  __syncthreads();

  // attn[c][d] = sum_p q'[p][c] * k[p][d]; 8x8 register tile per thread
  int tc = t >> 4, td = t & 15;
  int c0 = tc << 3, d0 = td << 3;
  float acc[8][8];
#pragma unroll
  for (int i = 0; i < 8; ++i)
#pragma unroll
    for (int j = 0; j < 8; ++j) acc[i][j] = 0.f;
  for (int p = 0; p < 64; ++p) {
    float4 qa = *(const float4*)&q_s[p][c0];
    float4 qb = *(const float4*)&q_s[p][c0 + 4];
    float4 ka = *(const float4*)&k_s[p][d0];
    float4 kb = *(const float4*)&k_s[p][d0 + 4];
    float qv[8] = {qa.x, qa.y, qa.z, qa.w, qb.x, qb.y, qb.z, qb.w};
    float kv[8] = {ka.x, ka.y, ka.z, ka.w, kb.x, kb.y, kb.z, kb.w};
#pragma unroll
    for (int i = 0; i < 8; ++i)
#pragma unroll
      for (int j = 0; j < 8; ++j) acc[i][j] = fmaf(qv[i], kv[j], acc[i][j]);
  }
  float* ao = attn_out + ((size_t)blk << 14);   // 128*128 per window
#pragma unroll
  for (int i = 0; i < 8; ++i) {
    float4 r0, r1;
    r0.x = fmaxf(acc[i][0], 0.f); r0.y = fmaxf(acc[i][1], 0.f);
    r0.z = fmaxf(acc[i][2], 0.f); r0.w = fmaxf(acc[i][3], 0.f);
    r1.x = fmaxf(acc[i][4], 0.f); r1.y = fmaxf(acc[i][5], 0.f);
    r1.z = fmaxf(acc[i][6], 0.f); r1.w = fmaxf(acc[i][7], 0.f);
    *(float4*)(ao + ((c0 + i) << 7) + d0) = r0;
    *(float4*)(ao + ((c0 + i) << 7) + d0 + 4) = r1;
  }
}

// ---------------- Kernel 2b: dw(v) + out = V * attn, windowed layout ----------
template <typename ST>
__global__ __launch_bounds__(256) void k_pv(const ST* __restrict__ qkv,
                                            const float* __restrict__ wdw,
                                            const float* __restrict__ attn,
                                            float* __restrict__ out_win) {
  __shared__ float v_s[64][136];
  __shared__ float halo[16][10][12];
  __shared__ float a_s[32][128];

  int blk = blockIdx.x;
  int b = blk >> 10, n = blk & 1023;
  int ih0 = (n >> 5) << 3, iw0 = (n & 31) << 3;
  int t = threadIdx.x;
  int ch_l = t & 15, pq = t >> 4;
  for (int cc = 0; cc < 8; ++cc) {
    __syncthreads();
    stage_halo(qkv, 2, b, cc, ih0, iw0, t, halo);
    __syncthreads();
    float wd[9];
#pragma unroll
    for (int kk = 0; kk < 9; ++kk) wd[kk] = wdw[(2 * CC + cc * 16 + ch_l) * 9 + kk];
#pragma unroll
    for (int u = 0; u < 4; ++u) {
      int px = pq + (u << 4);
      int pr = px >> 3, pc = px & 7;
      float v = 0.f;
#pragma unroll
      for (int r = 0; r < 3; ++r)
#pragma unroll
        for (int s = 0; s < 3; ++s) v = fmaf(wd[r * 3 + s], halo[ch_l][pr + r][pc + s], v);
      v_s[px][cc * 16 + ch_l] = v;
    }
  }

  // out[p][d] = sum_c v[p][c] * attn[c][d]; 4p x 8d tile per thread
  int tp = t >> 4, td = t & 15;
  int p0 = tp << 2, d0 = td << 3;
  float acc[4][8];
#pragma unroll
  for (int i = 0; i < 4; ++i)
#pragma unroll
    for (int j = 0; j < 8; ++j) acc[i][j] = 0.f;
  const float4* ab = (const float4*)(attn + ((size_t)blk << 14));
  for (int cc = 0; cc < 4; ++cc) {
    __syncthreads();
    for (int idx = t; idx < 1024; idx += 256) ((float4*)a_s)[idx] = ab[cc * 1024 + idx];
    __syncthreads();
    for (int cl = 0; cl < 32; ++cl) {
      int c = (cc << 5) + cl;
      float vv[4];
#pragma unroll
      for (int i = 0; i < 4; ++i) vv[i] = v_s[p0 + i][c];
      float4 aa = *(const float4*)&a_s[cl][d0];
      float4 abv = *(const float4*)&a_s[cl][d0 + 4];
      float av[8] = {aa.x, aa.y, aa.z, aa.w, abv.x, abv.y, abv.z, abv.w};
#pragma unroll
      for (int i = 0; i < 4; ++i)
#pragma unroll
        for (int j = 0; j < 8; ++j) acc[i][j] = fmaf(vv[i], av[j], acc[i][j]);
    }
  }
  float* ow = out_win + ((size_t)blk << 13);   // 64*128 per window
#pragma unroll
  for (int i = 0; i < 4; ++i) {
    float4 r0, r1;
    r0.x = acc[i][0]; r0.y = acc[i][1]; r0.z = acc[i][2]; r0.w = acc[i][3];
    r1.x = acc[i][4]; r1.y = acc[i][5]; r1.z = acc[i][6]; r1.w = acc[i][7];
    *(float4*)(ow + ((p0 + i) << 7) + d0) = r0;
    *(float4*)(ow + ((p0 + i) << 7) + d0 + 4) = r1;
  }
}

// ---------------- Kernel 3: proj 1x1 with unwindow + roll(+4,+4) fused --------
__global__ __launch_bounds__(256) void k_proj(const float* __restrict__ out_win,
                                              const float* __restrict__ wp,
                                              float* __restrict__ y) {
  int id = blockIdx.x * 256 + threadIdx.x;  // (b, n, p)
  int p = id & 63, bn = id >> 6;
  int b = bn >> 10, n = bn & 1023;
  int i_r = ((n >> 5) << 3) + (p >> 3);
  int j_r = ((n & 31) << 3) + (p & 7);
  int i_f = (i_r + 4) & 255, j_f = (j_r + 4) & 255;   // roll(+4,+4)
  float xr[CC];
  const float4* src = (const float4*)(out_win + (size_t)id * CC);
#pragma unroll
  for (int c4 = 0; c4 < CC / 4; ++c4) {
    float4 v = src[c4];
    xr[c4 * 4 + 0] = v.x; xr[c4 * 4 + 1] = v.y;
    xr[c4 * 4 + 2] = v.z; xr[c4 * 4 + 3] = v.w;
  }
  float* yp = y + (((size_t)b * CC) << 16) + (i_f << 8) + j_f;
  for (int o = 0; o < CC; ++o) {
    const float* wrow = wp + o * CC;   // uniform -> s_load
    float acc = 0.f;
#pragma unroll
    for (int c = 0; c < CC; ++c) acc = fmaf(wrow[c], xr[c], acc);
    yp[(size_t)o << 16] = acc;
  }
}

extern "C" void kernel_launch(void* const* d_in, const int* in_sizes, int n_in,
                              void* d_out, int out_size, void* d_ws, size_t ws_size,
                              hipStream_t stream) {
  const float* x = (const float*)d_in[0];
  const float* w_qkv = (const float*)d_in[1];
  const float* w_dw = (const float*)d_in[2];
  const float* w_proj = (const float*)d_in[3];
  const float* temp = (const float*)d_in[4];
  float* y = (float*)d_out;
  float* attn = (float*)d_out + (size_t)NB * CC * HW;   // 33,554,432 floats of y first

  const size_t qkv_elems = (size_t)3 * NB * CC * HW;    // 100,663,296
  if (ws_size >= qkv_elems * sizeof(float)) {
    // fp32 scratch path
    float* qkv = (float*)d_ws;
    float* out_win = (float*)d_ws;   // reuses q+k region (dead by k_pv time)
    k_qkv<float><<<1024, 256, 0, stream>>>(x, w_qkv, qkv);
    k_attn<float><<<4096, 256, 0, stream>>>(qkv, w_dw, temp, attn);
    k_pv<float><<<4096, 256, 0, stream>>>(qkv, w_dw, attn, out_win);
    k_proj<<<1024, 256, 0, stream>>>(out_win, w_proj, y);
  } else {
    // bf16 scratch fallback (qkv stored bf16, all math fp32)
    __hip_bfloat16* qkv = (__hip_bfloat16*)d_ws;
    float* out_win = (float*)d_ws;   // 128 MB over dead q+k bf16 regions
    k_qkv<__hip_bfloat16><<<1024, 256, 0, stream>>>(x, w_qkv, qkv);
    k_attn<__hip_bfloat16><<<4096, 256, 0, stream>>>(qkv, w_dw, temp, attn);
    k_pv<__hip_bfloat16><<<4096, 256, 0, stream>>>(qkv, w_dw, attn, out_win);
    k_proj<<<1024, 256, 0, stream>>>(out_win, w_proj, y);
  }
}

// Round 2
// 4371.365 us; speedup vs baseline: 1.8796x; 1.8796x over previous
//
#include <hip/hip_runtime.h>
#include <hip/hip_bf16.h>

// Problem constants
constexpr int NB = 4;        // batch
constexpr int CC = 128;      // channels
constexpr int HW = 65536;    // 256*256 pixels per (b, channel) plane
// windows: 32x32 = 1024 per batch, 8x8 = 64 px per window

__device__ __forceinline__ float from_st(float v) { return v; }
__device__ __forceinline__ float from_st(__hip_bfloat16 v) { return __bfloat162float(v); }
__device__ __forceinline__ void store_st(float* p, float v) { *p = v; }
__device__ __forceinline__ void store_st(__hip_bfloat16* p, float v) { *p = __float2bfloat16(v); }

// ---------------- Kernel 1: rolled 1x1 conv  qkv[g][b][c][h][w] (rolled space) ----------
template <typename ST>
__global__ __launch_bounds__(256) void k_qkv(const float* __restrict__ x,
                                             const float* __restrict__ wq,
                                             ST* __restrict__ qkv) {
  int id = blockIdx.x * 256 + threadIdx.x;     // (b, i, j)
  int b = id >> 16;
  int i = (id >> 8) & 255;
  int j = id & 255;
  int si = (i + 4) & 255, sj = (j + 4) & 255;  // roll(-4,-4): x_[i,j] = x[i+4, j+4]
  const float* xp = x + (((size_t)b * CC) << 16) + (si << 8) + sj;
  float xr[CC];
#pragma unroll
  for (int c = 0; c < CC; ++c) xr[c] = xp[(size_t)c << 16];
#pragma unroll 4
  for (int och = 0; och < 3 * CC; ++och) {
    const float* wrow = wq + och * CC;   // uniform -> s_load
    float acc = 0.f;
#pragma unroll
    for (int c = 0; c < CC; ++c) acc = fmaf(wrow[c], xr[c], acc);
    int g = och >> 7, cl = och & 127;
    store_st(&qkv[(((size_t)((g * NB + b) * CC + cl)) << 16) + (i << 8) + j], acc);
  }
}

// ------- dw-conv halo staging helper: stage 16 channels of a 10x10 halo --------
template <typename ST>
__device__ __forceinline__ void stage_halo(const ST* __restrict__ qkv, int g, int b,
                                           int cc, int ih0, int iw0, int t,
                                           float (*halo)[10][12]) {
  for (int idx = t; idx < 1600; idx += 256) {
    int ch = idx / 100, pos = idx - ch * 100;
    int r = pos / 10, cl = pos - r * 10;
    int ii = ih0 - 1 + r, jj = iw0 - 1 + cl;
    float v = 0.f;
    if ((unsigned)ii < 256u && (unsigned)jj < 256u)
      v = from_st(qkv[(((size_t)((g * NB + b) * CC + cc * 16 + ch)) << 16) + (ii << 8) + jj]);
    halo[ch][r][cl] = v;
  }
}

// ---------------- Kernel 2a: dw(q,k) + normalize + attn = relu(tau * Q^T K) -----------
template <typename ST>
__global__ __launch_bounds__(256) void k_attn(const ST* __restrict__ qkv,
                                              const float* __restrict__ wdw,
                                              const float* __restrict__ temp_p,
                                              float* __restrict__ attn_out) {
  __shared__ float q_s[64][132];
  __shared__ float k_s[64][132];
  __shared__ float halo[16][10][12];
  __shared__ float sumsq[2][64];
  __shared__ float pscale[64];

  int blk = blockIdx.x;              // b*1024 + n
  int b = blk >> 10, n = blk & 1023;
  int ih0 = (n >> 5) << 3, iw0 = (n & 31) << 3;   // window origin (rolled space)
  int t = threadIdx.x;
  if (t < 128) sumsq[t >> 6][t & 63] = 0.f;

  int ch_l = t & 15, pq = t >> 4;
#pragma unroll 1
  for (int g = 0; g < 2; ++g) {   // 0 = q, 1 = k
    float(*dst)[132] = (g == 0) ? q_s : k_s;
#pragma unroll 1
    for (int cc = 0; cc < 8; ++cc) {
      __syncthreads();
      stage_halo(qkv, g, b, cc, ih0, iw0, t, halo);
      __syncthreads();
      float wd[9];
#pragma unroll
      for (int kk = 0; kk < 9; ++kk) wd[kk] = wdw[(g * CC + cc * 16 + ch_l) * 9 + kk];
#pragma unroll
      for (int u = 0; u < 4; ++u) {
        int px = pq + (u << 4);
        int pr = px >> 3, pc = px & 7;
        float v = 0.f;
#pragma unroll
        for (int r = 0; r < 3; ++r)
#pragma unroll
          for (int s = 0; s < 3; ++s) v = fmaf(wd[r * 3 + s], halo[ch_l][pr + r][pc + s], v);
        dst[px][cc * 16 + ch_l] = v;
        float sq = v * v;                      // per-pixel sum of squares over channels
        sq += __shfl_xor(sq, 1);
        sq += __shfl_xor(sq, 2);
        sq += __shfl_xor(sq, 4);
        sq += __shfl_xor(sq, 8);
        if (ch_l == 0) sumsq[g][px] += sq;
      }
    }
  }
  __syncthreads();
  if (t < 64) {
    float nq = fmaxf(sqrtf(sumsq[0][t]), 1e-12f);
    float nk = fmaxf(sqrtf(sumsq[1][t]), 1e-12f);
    pscale[t] = temp_p[0] / (nq * nk);          // fold tau and both norms into q rows
  }
  __syncthreads();
  for (int idx = t; idx < 64 * 128; idx += 256) {
    int px = idx >> 7, c = idx & 127;
    q_s[px][c] *= pscale[px];
  }
  __syncthreads();

  // attn[c][d] = sum_p q'[p][c] * k[p][d]; 8x8 register tile per thread
  // NOTE: p-loop pinned to unroll 1 — full unroll (const trip 64) made LLVM
  // hoist ~1024 LDS loads, blow past 256 VGPRs, and spill acc to scratch
  // (round-1: 12.5 GB HBM traffic in k_pv from the same pattern).
  int tc = t >> 4, td = t & 15;
  int c0 = tc << 3, d0 = td << 3;
  float acc[8][8];
#pragma unroll
  for (int i = 0; i < 8; ++i)
#pragma unroll
    for (int j = 0; j < 8; ++j) acc[i][j] = 0.f;
#pragma unroll 1
  for (int p = 0; p < 64; ++p) {
    float4 qa = *(const float4*)&q_s[p][c0];
    float4 qb = *(const float4*)&q_s[p][c0 + 4];
    float4 ka = *(const float4*)&k_s[p][d0];
    float4 kb = *(const float4*)&k_s[p][d0 + 4];
    float qv[8] = {qa.x, qa.y, qa.z, qa.w, qb.x, qb.y, qb.z, qb.w};
    float kv[8] = {ka.x, ka.y, ka.z, ka.w, kb.x, kb.y, kb.z, kb.w};
#pragma unroll
    for (int i = 0; i < 8; ++i)
#pragma unroll
      for (int j = 0; j < 8; ++j) acc[i][j] = fmaf(qv[i], kv[j], acc[i][j]);
  }
  float* ao = attn_out + ((size_t)blk << 14);   // 128*128 per window
#pragma unroll
  for (int i = 0; i < 8; ++i) {
    float4 r0, r1;
    r0.x = fmaxf(acc[i][0], 0.f); r0.y = fmaxf(acc[i][1], 0.f);
    r0.z = fmaxf(acc[i][2], 0.f); r0.w = fmaxf(acc[i][3], 0.f);
    r1.x = fmaxf(acc[i][4], 0.f); r1.y = fmaxf(acc[i][5], 0.f);
    r1.z = fmaxf(acc[i][6], 0.f); r1.w = fmaxf(acc[i][7], 0.f);
    *(float4*)(ao + ((c0 + i) << 7) + d0) = r0;
    *(float4*)(ao + ((c0 + i) << 7) + d0 + 4) = r1;
  }
}

// ---------------- Kernel 2b: dw(v) + out = V * attn, windowed layout ----------
template <typename ST>
__global__ __launch_bounds__(256) void k_pv(const ST* __restrict__ qkv,
                                            const float* __restrict__ wdw,
                                            const float* __restrict__ attn,
                                            float* __restrict__ out_win) {
  __shared__ float v_s[64][132];
  __shared__ float halo[16][10][12];
  __shared__ float a_s[32][128];

  int blk = blockIdx.x;
  int b = blk >> 10, n = blk & 1023;
  int ih0 = (n >> 5) << 3, iw0 = (n & 31) << 3;
  int t = threadIdx.x;
  int ch_l = t & 15, pq = t >> 4;
#pragma unroll 1
  for (int cc = 0; cc < 8; ++cc) {
    __syncthreads();
    stage_halo(qkv, 2, b, cc, ih0, iw0, t, halo);
    __syncthreads();
    float wd[9];
#pragma unroll
    for (int kk = 0; kk < 9; ++kk) wd[kk] = wdw[(2 * CC + cc * 16 + ch_l) * 9 + kk];
#pragma unroll
    for (int u = 0; u < 4; ++u) {
      int px = pq + (u << 4);
      int pr = px >> 3, pc = px & 7;
      float v = 0.f;
#pragma unroll
      for (int r = 0; r < 3; ++r)
#pragma unroll
        for (int s = 0; s < 3; ++s) v = fmaf(wd[r * 3 + s], halo[ch_l][pr + r][pc + s], v);
      v_s[px][cc * 16 + ch_l] = v;
    }
  }

  // out[p][d] = sum_c v[p][c] * attn[c][d]; 4p x 8d tile per thread
  // cl-loop pinned to unroll 1 (see k_attn note — spill prevention).
  int tp = t >> 4, td = t & 15;
  int p0 = tp << 2, d0 = td << 3;
  float acc[4][8];
#pragma unroll
  for (int i = 0; i < 4; ++i)
#pragma unroll
    for (int j = 0; j < 8; ++j) acc[i][j] = 0.f;
  const float4* ab = (const float4*)(attn + ((size_t)blk << 14));
#pragma unroll 1
  for (int cc = 0; cc < 4; ++cc) {
    __syncthreads();
    for (int idx = t; idx < 1024; idx += 256) ((float4*)a_s)[idx] = ab[cc * 1024 + idx];
    __syncthreads();
#pragma unroll 1
    for (int cl = 0; cl < 32; ++cl) {
      int c = (cc << 5) + cl;
      float vv[4];
#pragma unroll
      for (int i = 0; i < 4; ++i) vv[i] = v_s[p0 + i][c];
      float4 aa = *(const float4*)&a_s[cl][d0];
      float4 abv = *(const float4*)&a_s[cl][d0 + 4];
      float av[8] = {aa.x, aa.y, aa.z, aa.w, abv.x, abv.y, abv.z, abv.w};
#pragma unroll
      for (int i = 0; i < 4; ++i)
#pragma unroll
        for (int j = 0; j < 8; ++j) acc[i][j] = fmaf(vv[i], av[j], acc[i][j]);
    }
  }
  float* ow = out_win + ((size_t)blk << 13);   // 64*128 per window
#pragma unroll
  for (int i = 0; i < 4; ++i) {
    float4 r0, r1;
    r0.x = acc[i][0]; r0.y = acc[i][1]; r0.z = acc[i][2]; r0.w = acc[i][3];
    r1.x = acc[i][4]; r1.y = acc[i][5]; r1.z = acc[i][6]; r1.w = acc[i][7];
    *(float4*)(ow + ((p0 + i) << 7) + d0) = r0;
    *(float4*)(ow + ((p0 + i) << 7) + d0 + 4) = r1;
  }
}

// ---------------- Kernel 3: proj 1x1 with unwindow + roll(+4,+4) fused --------
__global__ __launch_bounds__(256) void k_proj(const float* __restrict__ out_win,
                                              const float* __restrict__ wp,
                                              float* __restrict__ y) {
  int id = blockIdx.x * 256 + threadIdx.x;  // (b, n, p)
  int p = id & 63, bn = id >> 6;
  int b = bn >> 10, n = bn & 1023;
  int i_r = ((n >> 5) << 3) + (p >> 3);
  int j_r = ((n & 31) << 3) + (p & 7);
  int i_f = (i_r + 4) & 255, j_f = (j_r + 4) & 255;   // roll(+4,+4)
  float xr[CC];
  const float4* src = (const float4*)(out_win + (size_t)id * CC);
#pragma unroll
  for (int c4 = 0; c4 < CC / 4; ++c4) {
    float4 v = src[c4];
    xr[c4 * 4 + 0] = v.x; xr[c4 * 4 + 1] = v.y;
    xr[c4 * 4 + 2] = v.z; xr[c4 * 4 + 3] = v.w;
  }
  float* yp = y + (((size_t)b * CC) << 16) + (i_f << 8) + j_f;
#pragma unroll 4
  for (int o = 0; o < CC; ++o) {
    const float* wrow = wp + o * CC;   // uniform -> s_load
    float acc = 0.f;
#pragma unroll
    for (int c = 0; c < CC; ++c) acc = fmaf(wrow[c], xr[c], acc);
    yp[(size_t)o << 16] = acc;
  }
}

extern "C" void kernel_launch(void* const* d_in, const int* in_sizes, int n_in,
                              void* d_out, int out_size, void* d_ws, size_t ws_size,
                              hipStream_t stream) {
  const float* x = (const float*)d_in[0];
  const float* w_qkv = (const float*)d_in[1];
  const float* w_dw = (const float*)d_in[2];
  const float* w_proj = (const float*)d_in[3];
  const float* temp = (const float*)d_in[4];
  float* y = (float*)d_out;
  float* attn = (float*)d_out + (size_t)NB * CC * HW;   // 33,554,432 floats of y first

  const size_t qkv_elems = (size_t)3 * NB * CC * HW;    // 100,663,296
  if (ws_size >= qkv_elems * sizeof(float)) {
    // fp32 scratch path
    float* qkv = (float*)d_ws;
    float* out_win = (float*)d_ws;   // reuses q+k region (dead by k_pv time)
    k_qkv<float><<<1024, 256, 0, stream>>>(x, w_qkv, qkv);
    k_attn<float><<<4096, 256, 0, stream>>>(qkv, w_dw, temp, attn);
    k_pv<float><<<4096, 256, 0, stream>>>(qkv, w_dw, attn, out_win);
    k_proj<<<1024, 256, 0, stream>>>(out_win, w_proj, y);
  } else {
    // bf16 scratch fallback (qkv stored bf16, all math fp32)
    __hip_bfloat16* qkv = (__hip_bfloat16*)d_ws;
    float* out_win = (float*)d_ws;   // 128 MB over dead q+k bf16 regions
    k_qkv<__hip_bfloat16><<<1024, 256, 0, stream>>>(x, w_qkv, qkv);
    k_attn<__hip_bfloat16><<<4096, 256, 0, stream>>>(qkv, w_dw, temp, attn);
    k_pv<__hip_bfloat16><<<4096, 256, 0, stream>>>(qkv, w_dw, attn, out_win);
    k_proj<<<1024, 256, 0, stream>>>(out_win, w_proj, y);
  }
}

// Round 3
// 1481.936 us; speedup vs baseline: 5.5444x; 2.9498x over previous
//
#include <hip/hip_runtime.h>
#include <hip/hip_bf16.h>

// Problem constants
constexpr int NB = 4;        // batch
constexpr int CC = 128;      // channels
constexpr int HW = 65536;    // 256*256 pixels per (b, channel) plane
// windows: 32x32 = 1024 per batch, 8x8 = 64 px per window

using bf16x8 = __attribute__((ext_vector_type(8))) short;   // MFMA A/B frag (4 VGPR)
using f32x4  = __attribute__((ext_vector_type(4))) float;   // MFMA C/D frag

__device__ __forceinline__ unsigned short f2bf(float f) {
  // round-to-nearest-even bf16 (no NaN handling needed for this data)
  unsigned u = __builtin_bit_cast(unsigned, f);
  u += 0x7FFFu + ((u >> 16) & 1u);
  return (unsigned short)(u >> 16);
}

// =======================================================================
// Kernel 1: rolled 1x1 conv as bf16 MFMA GEMM.
//   qkv[och][b-pix] = sum_c W[och][c] * x[b][c][rolled pix]
// Block = one half-row (128 px) of one (b, i): stage X tile [128 px][128 c]
// as bf16 in LDS (B^T layout: lane reads 8 contiguous K), W A-frags from
// global (L2-resident). Verified frag pattern: m92/m97 (A [m][k], B^T [n][k],
// 8-contig-K per lane via b128), D col=lane&15, row=(lane>>4)*4+reg (m89).
// =======================================================================
__global__ __launch_bounds__(256) void k_qkv_mfma(const float* __restrict__ x,
                                                  const float* __restrict__ wq,
                                                  __hip_bfloat16* __restrict__ qkv) {
  __shared__ unsigned short x_s[128 * 136];   // [px][c], pad 136 -> 2-way-free banks

  int blk = blockIdx.x;                 // 4 b x 256 i x 2 j-half
  int b = blk >> 9, i = (blk >> 1) & 255, jh = blk & 1;
  int j0 = jh << 7;
  int si = (i + 4) & 255;               // roll(-4): source row
  int t = threadIdx.x;

  // ---- stage: x_s[px][c] = bf16(x[b][c][si][(j0+px+4)&255]), c-pair per thread
  {
    int c0 = (t & 63) << 1;             // channel pair
    int jb = (t >> 6) << 5;             // 32-px strip
    const float* xr0 = x + (((size_t)(b * CC + c0)) << 16) + (si << 8);
    const float* xr1 = xr0 + HW;
#pragma unroll
    for (int u = 0; u < 8; ++u) {
      int jj = jb + (u << 2);           // px base within tile
      int sj = j0 + jj + 4;             // source col (may wrap past 255)
      float v0[4], v1[4];
      if (sj + 3 <= 255) {
        *(float4*)v0 = *(const float4*)(xr0 + sj);
        *(float4*)v1 = *(const float4*)(xr1 + sj);
      } else {
#pragma unroll
        for (int e = 0; e < 4; ++e) {
          int s = (sj + e) & 255;
          v0[e] = xr0[s];
          v1[e] = xr1[s];
        }
      }
#pragma unroll
      for (int e = 0; e < 4; ++e) {
        unsigned pk = (unsigned)f2bf(v0[e]) | ((unsigned)f2bf(v1[e]) << 16);
        *(unsigned*)&x_s[(jj + e) * 136 + c0] = pk;
      }
    }
  }
  __syncthreads();

  int w = t >> 6;                       // wave id (0..3)
  int lane = t & 63;
  int col = lane & 15;                  // N (pixel) / M (och row) offset
  int kg = lane >> 4;                   // K group (8 contiguous K each)

#pragma unroll 1
  for (int oi = 0; oi < 3; ++oi) {      // 3 x 128 output channels
    int m0 = oi * 128 + w * 32;         // this wave's 32 och
    // A-frags: 2 m-tiles x 4 k-steps, from global fp32 -> bf16
    bf16x8 afr[2][4];
#pragma unroll
    for (int mt = 0; mt < 2; ++mt) {
      const float* wr = wq + (m0 + mt * 16 + col) * CC + kg * 8;
#pragma unroll
      for (int ks = 0; ks < 4; ++ks) {
        float wa[4], wb[4];
        *(float4*)wa = *(const float4*)(wr + ks * 32);
        *(float4*)wb = *(const float4*)(wr + ks * 32 + 4);
        bf16x8 f;
#pragma unroll
        for (int e = 0; e < 4; ++e) {
          f[e] = (short)f2bf(wa[e]);
          f[e + 4] = (short)f2bf(wb[e]);
        }
        afr[mt][ks] = f;
      }
    }
#pragma unroll 1
    for (int n = 0; n < 8; ++n) {       // 8 n-tiles x 16 px = 128 px
      int px = n * 16 + col;
      f32x4 acc0 = {0.f, 0.f, 0.f, 0.f};
      f32x4 acc1 = {0.f, 0.f, 0.f, 0.f};
#pragma unroll
      for (int ks = 0; ks < 4; ++ks) {
        bf16x8 bfr = *(const bf16x8*)&x_s[px * 136 + ks * 32 + kg * 8];
        acc0 = __builtin_amdgcn_mfma_f32_16x16x32_bf16(afr[0][ks], bfr, acc0, 0, 0, 0);
        acc1 = __builtin_amdgcn_mfma_f32_16x16x32_bf16(afr[1][ks], bfr, acc1, 0, 0, 0);
      }
      int j = j0 + n * 16 + col;
#pragma unroll
      for (int r = 0; r < 4; ++r) {
        int och0 = m0 + kg * 4 + r;
        int och1 = m0 + 16 + kg * 4 + r;
        int g0 = och0 >> 7, c0 = och0 & 127;
        int g1 = och1 >> 7, c1 = och1 & 127;
        qkv[(((size_t)((g0 * NB + b) * CC + c0)) << 16) + (i << 8) + j] =
            __float2bfloat16(acc0[r]);
        qkv[(((size_t)((g1 * NB + b) * CC + c1)) << 16) + (i << 8) + j] =
            __float2bfloat16(acc1[r]);
      }
    }
  }
}

// ------- dw-conv halo staging helper: stage 16 channels of a 10x10 halo --------
__device__ __forceinline__ void stage_halo(const __hip_bfloat16* __restrict__ qkv,
                                           int g, int b, int cc, int ih0, int iw0,
                                           int t, float (*halo)[10][12]) {
  for (int idx = t; idx < 1600; idx += 256) {
    int ch = idx / 100, pos = idx - ch * 100;
    int r = pos / 10, cl = pos - r * 10;
    int ii = ih0 - 1 + r, jj = iw0 - 1 + cl;
    float v = 0.f;
    if ((unsigned)ii < 256u && (unsigned)jj < 256u)
      v = __bfloat162float(
          qkv[(((size_t)((g * NB + b) * CC + cc * 16 + ch)) << 16) + (ii << 8) + jj]);
    halo[ch][r][cl] = v;
  }
}

// ---------------- Kernel 2a: dw(q,k) + normalize + attn = relu(tau * Q^T K) -----------
__global__ __launch_bounds__(256) void k_attn(const __hip_bfloat16* __restrict__ qkv,
                                              const float* __restrict__ wdw,
                                              const float* __restrict__ temp_p,
                                              float* __restrict__ attn_out) {
  __shared__ float q_s[64][132];
  __shared__ float k_s[64][132];
  __shared__ float halo[16][10][12];
  __shared__ float sumsq[2][64];
  __shared__ float pscale[64];

  int blk = blockIdx.x;              // b*1024 + n
  int b = blk >> 10, n = blk & 1023;
  int ih0 = (n >> 5) << 3, iw0 = (n & 31) << 3;   // window origin (rolled space)
  int t = threadIdx.x;
  if (t < 128) sumsq[t >> 6][t & 63] = 0.f;

  int ch_l = t & 15, pq = t >> 4;
#pragma unroll 1
  for (int g = 0; g < 2; ++g) {   // 0 = q, 1 = k
    float(*dst)[132] = (g == 0) ? q_s : k_s;
#pragma unroll 1
    for (int cc = 0; cc < 8; ++cc) {
      __syncthreads();
      stage_halo(qkv, g, b, cc, ih0, iw0, t, halo);
      __syncthreads();
      float wd[9];
#pragma unroll
      for (int kk = 0; kk < 9; ++kk) wd[kk] = wdw[(g * CC + cc * 16 + ch_l) * 9 + kk];
#pragma unroll
      for (int u = 0; u < 4; ++u) {
        int px = pq + (u << 4);
        int pr = px >> 3, pc = px & 7;
        float v = 0.f;
#pragma unroll
        for (int r = 0; r < 3; ++r)
#pragma unroll
          for (int s = 0; s < 3; ++s) v = fmaf(wd[r * 3 + s], halo[ch_l][pr + r][pc + s], v);
        dst[px][cc * 16 + ch_l] = v;
        float sq = v * v;                      // per-pixel sum of squares over channels
        sq += __shfl_xor(sq, 1);
        sq += __shfl_xor(sq, 2);
        sq += __shfl_xor(sq, 4);
        sq += __shfl_xor(sq, 8);
        if (ch_l == 0) sumsq[g][px] += sq;
      }
    }
  }
  __syncthreads();
  if (t < 64) {
    float nq = fmaxf(sqrtf(sumsq[0][t]), 1e-12f);
    float nk = fmaxf(sqrtf(sumsq[1][t]), 1e-12f);
    pscale[t] = temp_p[0] / (nq * nk);          // fold tau and both norms into q rows
  }
  __syncthreads();
  for (int idx = t; idx < 64 * 128; idx += 256) {
    int px = idx >> 7, c = idx & 127;
    q_s[px][c] *= pscale[px];
  }
  __syncthreads();

  // attn[c][d] = sum_p q'[p][c] * k[p][d]; 8x8 register tile per thread
  // p-loop pinned to unroll 1 (spill prevention, see round-1).
  int tc = t >> 4, td = t & 15;
  int c0 = tc << 3, d0 = td << 3;
  float acc[8][8];
#pragma unroll
  for (int i = 0; i < 8; ++i)
#pragma unroll
    for (int j = 0; j < 8; ++j) acc[i][j] = 0.f;
#pragma unroll 1
  for (int p = 0; p < 64; ++p) {
    float4 qa = *(const float4*)&q_s[p][c0];
    float4 qb = *(const float4*)&q_s[p][c0 + 4];
    float4 ka = *(const float4*)&k_s[p][d0];
    float4 kb = *(const float4*)&k_s[p][d0 + 4];
    float qv[8] = {qa.x, qa.y, qa.z, qa.w, qb.x, qb.y, qb.z, qb.w};
    float kv[8] = {ka.x, ka.y, ka.z, ka.w, kb.x, kb.y, kb.z, kb.w};
#pragma unroll
    for (int i = 0; i < 8; ++i)
#pragma unroll
      for (int j = 0; j < 8; ++j) acc[i][j] = fmaf(qv[i], kv[j], acc[i][j]);
  }
  float* ao = attn_out + ((size_t)blk << 14);   // 128*128 per window
#pragma unroll
  for (int i = 0; i < 8; ++i) {
    float4 r0, r1;
    r0.x = fmaxf(acc[i][0], 0.f); r0.y = fmaxf(acc[i][1], 0.f);
    r0.z = fmaxf(acc[i][2], 0.f); r0.w = fmaxf(acc[i][3], 0.f);
    r1.x = fmaxf(acc[i][4], 0.f); r1.y = fmaxf(acc[i][5], 0.f);
    r1.z = fmaxf(acc[i][6], 0.f); r1.w = fmaxf(acc[i][7], 0.f);
    *(float4*)(ao + ((c0 + i) << 7) + d0) = r0;
    *(float4*)(ao + ((c0 + i) << 7) + d0 + 4) = r1;
  }
}

// ---------------- Kernel 2b: dw(v) + out = V * attn, windowed bf16 layout ----------
__global__ __launch_bounds__(256) void k_pv(const __hip_bfloat16* __restrict__ qkv,
                                            const float* __restrict__ wdw,
                                            const float* __restrict__ attn,
                                            __hip_bfloat16* __restrict__ out_win) {
  __shared__ float v_s[64][132];
  __shared__ float halo[16][10][12];
  __shared__ float a_s[32][128];

  int blk = blockIdx.x;
  int b = blk >> 10, n = blk & 1023;
  int ih0 = (n >> 5) << 3, iw0 = (n & 31) << 3;
  int t = threadIdx.x;
  int ch_l = t & 15, pq = t >> 4;
#pragma unroll 1
  for (int cc = 0; cc < 8; ++cc) {
    __syncthreads();
    stage_halo(qkv, 2, b, cc, ih0, iw0, t, halo);
    __syncthreads();
    float wd[9];
#pragma unroll
    for (int kk = 0; kk < 9; ++kk) wd[kk] = wdw[(2 * CC + cc * 16 + ch_l) * 9 + kk];
#pragma unroll
    for (int u = 0; u < 4; ++u) {
      int px = pq + (u << 4);
      int pr = px >> 3, pc = px & 7;
      float v = 0.f;
#pragma unroll
      for (int r = 0; r < 3; ++r)
#pragma unroll
        for (int s = 0; s < 3; ++s) v = fmaf(wd[r * 3 + s], halo[ch_l][pr + r][pc + s], v);
      v_s[px][cc * 16 + ch_l] = v;
    }
  }

  // out[p][d] = sum_c v[p][c] * attn[c][d]; 4p x 8d tile per thread
  // cl-loop pinned to unroll 1 (spill prevention).
  int tp = t >> 4, td = t & 15;
  int p0 = tp << 2, d0 = td << 3;
  float acc[4][8];
#pragma unroll
  for (int i = 0; i < 4; ++i)
#pragma unroll
    for (int j = 0; j < 8; ++j) acc[i][j] = 0.f;
  const float4* ab = (const float4*)(attn + ((size_t)blk << 14));
#pragma unroll 1
  for (int cc = 0; cc < 4; ++cc) {
    __syncthreads();
    for (int idx = t; idx < 1024; idx += 256) ((float4*)a_s)[idx] = ab[cc * 1024 + idx];
    __syncthreads();
#pragma unroll 1
    for (int cl = 0; cl < 32; ++cl) {
      int c = (cc << 5) + cl;
      float vv[4];
#pragma unroll
      for (int i = 0; i < 4; ++i) vv[i] = v_s[p0 + i][c];
      float4 aa = *(const float4*)&a_s[cl][d0];
      float4 abv = *(const float4*)&a_s[cl][d0 + 4];
      float av[8] = {aa.x, aa.y, aa.z, aa.w, abv.x, abv.y, abv.z, abv.w};
#pragma unroll
      for (int i = 0; i < 4; ++i)
#pragma unroll
        for (int j = 0; j < 8; ++j) acc[i][j] = fmaf(vv[i], av[j], acc[i][j]);
    }
  }
  __hip_bfloat16* ow = out_win + ((size_t)blk << 13);   // 64*128 per window
#pragma unroll
  for (int i = 0; i < 4; ++i) {
    unsigned short o8[8];
#pragma unroll
    for (int j = 0; j < 8; ++j) o8[j] = f2bf(acc[i][j]);
    *(uint4*)(ow + ((p0 + i) << 7) + d0) = *(const uint4*)o8;
  }
}

// =======================================================================
// Kernel 3: proj 1x1 as bf16 MFMA GEMM, unwindow + roll(+4,+4) fused in store.
//   y[o][pix] = sum_c Wp[o][c] * out_win[pix][c]
// out_win is ALREADY B^T layout ([pix][c], c contiguous) -> B-frags load
// directly from global. Wp staged once per block to LDS bf16.
// Block = 4 windows; wave = 1 window (64 px = 4 n-tiles), all 128 och in regs.
// =======================================================================
__global__ __launch_bounds__(256) void k_proj_mfma(const __hip_bfloat16* __restrict__ out_win,
                                                   const float* __restrict__ wp,
                                                   float* __restrict__ y) {
  __shared__ unsigned short w_s[128 * 136];   // [och][c] bf16

  int t = threadIdx.x;
  // stage Wp -> LDS bf16
  {
    int och = t >> 1, ch0 = (t & 1) << 6;
    const float* wr = wp + och * CC + ch0;
#pragma unroll
    for (int u = 0; u < 32; ++u) {
      float2 v = *(const float2*)(wr + 2 * u);
      unsigned pk = (unsigned)f2bf(v.x) | ((unsigned)f2bf(v.y) << 16);
      *(unsigned*)&w_s[och * 136 + ch0 + 2 * u] = pk;
    }
  }
  __syncthreads();

  int w = t >> 6, lane = t & 63;
  int col = lane & 15, kg = lane >> 4;
  int bn = blockIdx.x * 4 + w;          // this wave's window
  int b = bn >> 10, n = bn & 1023;
  const __hip_bfloat16* ob = out_win + ((size_t)bn << 13);

  // all 128 och A-frags in regs: 8 m-tiles x 4 k-steps (128 VGPR)
  bf16x8 afr[8][4];
#pragma unroll
  for (int mt = 0; mt < 8; ++mt)
#pragma unroll
    for (int ks = 0; ks < 4; ++ks)
      afr[mt][ks] = *(const bf16x8*)&w_s[(mt * 16 + col) * 136 + ks * 32 + kg * 8];

#pragma unroll 1
  for (int nt = 0; nt < 4; ++nt) {      // 4 n-tiles x 16 px = 64 px (one window)
    int p = nt * 16 + col;
    bf16x8 bfr[4];
#pragma unroll
    for (int ks = 0; ks < 4; ++ks)
      bfr[ks] = *(const bf16x8*)(ob + p * CC + ks * 32 + kg * 8);
    // output pixel position (unwindow + roll +4)
    int i_f = (((n >> 5) << 3) + (p >> 3) + 4) & 255;
    int j_f = (((n & 31) << 3) + (p & 7) + 4) & 255;
    float* yp = y + (((size_t)b * CC) << 16) + (i_f << 8) + j_f;
#pragma unroll
    for (int mt = 0; mt < 8; ++mt) {
      f32x4 acc = {0.f, 0.f, 0.f, 0.f};
#pragma unroll
      for (int ks = 0; ks < 4; ++ks)
        acc = __builtin_amdgcn_mfma_f32_16x16x32_bf16(afr[mt][ks], bfr[ks], acc, 0, 0, 0);
#pragma unroll
      for (int r = 0; r < 4; ++r) {
        int och = mt * 16 + kg * 4 + r;
        yp[(size_t)och << 16] = acc[r];
      }
    }
  }
}

extern "C" void kernel_launch(void* const* d_in, const int* in_sizes, int n_in,
                              void* d_out, int out_size, void* d_ws, size_t ws_size,
                              hipStream_t stream) {
  const float* x = (const float*)d_in[0];
  const float* w_qkv = (const float*)d_in[1];
  const float* w_dw = (const float*)d_in[2];
  const float* w_proj = (const float*)d_in[3];
  const float* temp = (const float*)d_in[4];
  float* y = (float*)d_out;
  float* attn = (float*)d_out + (size_t)NB * CC * HW;   // y first, then attn

  // d_ws layout (bf16): qkv [3][b][c][hw] = 201 MB; out_win (67 MB) reuses the
  // q region, which is dead after k_attn.
  __hip_bfloat16* qkv = (__hip_bfloat16*)d_ws;
  __hip_bfloat16* out_win = (__hip_bfloat16*)d_ws;

  k_qkv_mfma<<<2048, 256, 0, stream>>>(x, w_qkv, qkv);
  k_attn<<<4096, 256, 0, stream>>>(qkv, w_dw, temp, attn);
  k_pv<<<4096, 256, 0, stream>>>(qkv, w_dw, attn, out_win);
  k_proj_mfma<<<1024, 256, 0, stream>>>(out_win, w_proj, y);
}

// Round 6
// 1199.718 us; speedup vs baseline: 6.8486x; 1.2352x over previous
//
#include <hip/hip_runtime.h>
#include <hip/hip_bf16.h>

// Problem constants
constexpr int NB = 4;        // batch
constexpr int CC = 128;      // channels
constexpr int HW = 65536;    // 256*256 pixels per (b, channel) plane
// windows: 32x32 = 1024 per batch, 8x8 = 64 px per window

using bf16x8 = __attribute__((ext_vector_type(8))) short;   // MFMA A/B frag (4 VGPR)
using f32x4  = __attribute__((ext_vector_type(4))) float;   // MFMA C/D frag

__device__ __forceinline__ unsigned short f2bf(float f) {
  // round-to-nearest-even bf16
  unsigned u = __builtin_bit_cast(unsigned, f);
  u += 0x7FFFu + ((u >> 16) & 1u);
  return (unsigned short)(u >> 16);
}
__device__ __forceinline__ float bf2f(unsigned short s) {
  return __builtin_bit_cast(float, (unsigned)s << 16);
}

// =======================================================================
// Kernel 1: rolled 1x1 conv as bf16 MFMA GEMM (unchanged from round 3).
// =======================================================================
__global__ __launch_bounds__(256) void k_qkv_mfma(const float* __restrict__ x,
                                                  const float* __restrict__ wq,
                                                  __hip_bfloat16* __restrict__ qkv) {
  __shared__ unsigned short x_s[128 * 136];   // [px][c]

  int blk = blockIdx.x;                 // 4 b x 256 i x 2 j-half
  int b = blk >> 9, i = (blk >> 1) & 255, jh = blk & 1;
  int j0 = jh << 7;
  int si = (i + 4) & 255;               // roll(-4): source row
  int t = threadIdx.x;

  {
    int c0 = (t & 63) << 1;             // channel pair
    int jb = (t >> 6) << 5;             // 32-px strip
    const float* xr0 = x + (((size_t)(b * CC + c0)) << 16) + (si << 8);
    const float* xr1 = xr0 + HW;
#pragma unroll
    for (int u = 0; u < 8; ++u) {
      int jj = jb + (u << 2);
      int sj = j0 + jj + 4;
      float v0[4], v1[4];
      if (sj + 3 <= 255) {
        *(float4*)v0 = *(const float4*)(xr0 + sj);
        *(float4*)v1 = *(const float4*)(xr1 + sj);
      } else {
#pragma unroll
        for (int e = 0; e < 4; ++e) {
          int s = (sj + e) & 255;
          v0[e] = xr0[s];
          v1[e] = xr1[s];
        }
      }
#pragma unroll
      for (int e = 0; e < 4; ++e) {
        unsigned pk = (unsigned)f2bf(v0[e]) | ((unsigned)f2bf(v1[e]) << 16);
        *(unsigned*)&x_s[(jj + e) * 136 + c0] = pk;
      }
    }
  }
  __syncthreads();

  int w = t >> 6;
  int lane = t & 63;
  int col = lane & 15;
  int kg = lane >> 4;

#pragma unroll 1
  for (int oi = 0; oi < 3; ++oi) {
    int m0 = oi * 128 + w * 32;
    bf16x8 afr[2][4];
#pragma unroll
    for (int mt = 0; mt < 2; ++mt) {
      const float* wr = wq + (m0 + mt * 16 + col) * CC + kg * 8;
#pragma unroll
      for (int ks = 0; ks < 4; ++ks) {
        float wa[4], wb[4];
        *(float4*)wa = *(const float4*)(wr + ks * 32);
        *(float4*)wb = *(const float4*)(wr + ks * 32 + 4);
        bf16x8 f;
#pragma unroll
        for (int e = 0; e < 4; ++e) {
          f[e] = (short)f2bf(wa[e]);
          f[e + 4] = (short)f2bf(wb[e]);
        }
        afr[mt][ks] = f;
      }
    }
#pragma unroll 1
    for (int n = 0; n < 8; ++n) {
      int px = n * 16 + col;
      f32x4 acc0 = {0.f, 0.f, 0.f, 0.f};
      f32x4 acc1 = {0.f, 0.f, 0.f, 0.f};
#pragma unroll
      for (int ks = 0; ks < 4; ++ks) {
        bf16x8 bfr = *(const bf16x8*)&x_s[px * 136 + ks * 32 + kg * 8];
        acc0 = __builtin_amdgcn_mfma_f32_16x16x32_bf16(afr[0][ks], bfr, acc0, 0, 0, 0);
        acc1 = __builtin_amdgcn_mfma_f32_16x16x32_bf16(afr[1][ks], bfr, acc1, 0, 0, 0);
      }
      int j = j0 + n * 16 + col;
#pragma unroll
      for (int r = 0; r < 4; ++r) {
        int och0 = m0 + kg * 4 + r;
        int och1 = m0 + 16 + kg * 4 + r;
        int g0 = och0 >> 7, c0 = och0 & 127;
        int g1 = och1 >> 7, c1 = och1 & 127;
        qkv[(((size_t)((g0 * NB + b) * CC + c0)) << 16) + (i << 8) + j] =
            __float2bfloat16(acc0[r]);
        qkv[(((size_t)((g1 * NB + b) * CC + c1)) << 16) + (i << 8) + j] =
            __float2bfloat16(acc1[r]);
      }
    }
  }
}

// =======================================================================
// Kernel 2a: dw(q,k) + normalize + attn = relu(tau * Q^T K) via bf16 MFMA.
// ROUND-5 BUG FIX: dw wrote dst[px][ch] into the [c][p] (stride-72) tile —
// transposed indexing corrupted rows 0..63 and left rows 64..127 stale
// (absmax 2e37 from stale LDS read as bf16). Now dst[ch][px].
// =======================================================================
__global__ __launch_bounds__(256) void k_attn(const __hip_bfloat16* __restrict__ qkv,
                                              const float* __restrict__ wdw,
                                              const float* __restrict__ temp_p,
                                              float* __restrict__ attn_out) {
  __shared__ unsigned short halo_s[128 * 124];   // [ch][r*12+cl] bf16 (10x10 valid)
  __shared__ unsigned short q_t[128][72];        // [c][p] bf16 (stride 144 B, 16B-mult)
  __shared__ unsigned short k_t[128][72];
  __shared__ float sumsq_s[64];
  __shared__ float ps[64];

  int blk = blockIdx.x;              // b*1024 + n
  int b = blk >> 10, n = blk & 1023;
  int ih0 = (n >> 5) << 3, iw0 = (n & 31) << 3;
  int t = threadIdx.x;
  int ch_l = t & 15, pq = t >> 4;    // pq 0..15
  float tau = temp_p[0];

#pragma unroll 1
  for (int g = 0; g < 2; ++g) {      // 0 = q, 1 = k
    __syncthreads();                 // halo_s reuse / scale-pass reads done
    {
      const __hip_bfloat16* base = qkv + (((size_t)((g * NB + b) * CC)) << 16);
#pragma unroll 1
      for (int i = 0; i < 50; ++i) { // 12800 = 50*256 halo elems
        int idx = i * 256 + t;
        int ch = idx / 100;
        int pos = idx - ch * 100;
        int r = pos / 10, cl = pos - r * 10;
        int ii = ih0 - 1 + r, jj = iw0 - 1 + cl;
        unsigned short hv = 0;
        if ((unsigned)ii < 256u && (unsigned)jj < 256u)
          hv = __builtin_bit_cast(unsigned short,
                                  base[((size_t)ch << 16) + (ii << 8) + jj]);
        halo_s[ch * 124 + r * 12 + cl] = hv;
      }
    }
    __syncthreads();
    // dw conv -> dst[c][p] bf16 (unscaled) + per-pixel sumsq
    unsigned short (*dst)[72] = g ? k_t : q_t;
    float ssq[4] = {0.f, 0.f, 0.f, 0.f};
#pragma unroll 1
    for (int ch_hi = 0; ch_hi < 8; ++ch_hi) {
      int ch = ch_hi * 16 + ch_l;
      float wd[9];
#pragma unroll
      for (int kk = 0; kk < 9; ++kk) wd[kk] = wdw[(g * CC + ch) * 9 + kk];
      const unsigned short* hb = &halo_s[ch * 124];
#pragma unroll
      for (int u = 0; u < 4; ++u) {
        int px = pq + (u << 4);
        int pr = px >> 3, pc = px & 7;
        float v = 0.f;
#pragma unroll
        for (int r = 0; r < 3; ++r)
#pragma unroll
          for (int s = 0; s < 3; ++s)
            v = fmaf(wd[r * 3 + s], bf2f(hb[(pr + r) * 12 + pc + s]), v);
        dst[ch][px] = f2bf(v);         // [c][p] layout (FIXED)
        float sq = v * v;              // exact (pre-rounding) sumsq
        sq += __shfl_xor(sq, 1);
        sq += __shfl_xor(sq, 2);
        sq += __shfl_xor(sq, 4);
        sq += __shfl_xor(sq, 8);
        ssq[u] += sq;                  // butterfly -> all 16 lanes hold sum
      }
    }
    if (ch_l == 0) {
#pragma unroll
      for (int u = 0; u < 4; ++u) sumsq_s[pq + (u << 4)] = ssq[u];
    }
    __syncthreads();
    if (t < 64) {
      float nr = fmaxf(sqrtf(sumsq_s[t]), 1e-12f);
      ps[t] = g ? (tau / nr) : (1.f / nr);   // tau folded into k's scale
    }
    __syncthreads();
    // in-place per-pixel rescale (bf16 pairs)
#pragma unroll 1
    for (int it = 0; it < 16; ++it) {
      int pi = it * 256 + t;
      int c = pi >> 5, pp = pi & 31;
      unsigned w2 = *(unsigned*)&dst[c][2 * pp];
      float2 s2 = *(const float2*)&ps[2 * pp];
      float lo = __builtin_bit_cast(float, w2 << 16) * s2.x;
      float hi = __builtin_bit_cast(float, w2 & 0xFFFF0000u) * s2.y;
      *(unsigned*)&dst[c][2 * pp] = (unsigned)f2bf(lo) | ((unsigned)f2bf(hi) << 16);
    }
  }
  __syncthreads();

  // attn[c][d] = sum_p q_t[c][p] * k_t[d][p]; wave wv owns c-band wv*32..+31.
  int wv = t >> 6, lane = t & 63;
  int col = lane & 15, kg = lane >> 4;
  int c0 = wv * 32;
  bf16x8 afr[2][2];
#pragma unroll
  for (int mt = 0; mt < 2; ++mt)
#pragma unroll
    for (int ks = 0; ks < 2; ++ks)
      afr[mt][ks] = *(const bf16x8*)&q_t[c0 + mt * 16 + col][ks * 32 + kg * 8];
  float* ao = attn_out + ((size_t)blk << 14);   // 128*128 per window
#pragma unroll
  for (int dt = 0; dt < 8; ++dt) {
    bf16x8 b0 = *(const bf16x8*)&k_t[dt * 16 + col][kg * 8];
    bf16x8 b1 = *(const bf16x8*)&k_t[dt * 16 + col][32 + kg * 8];
    f32x4 a0 = {0.f, 0.f, 0.f, 0.f};
    f32x4 a1 = {0.f, 0.f, 0.f, 0.f};
    a0 = __builtin_amdgcn_mfma_f32_16x16x32_bf16(afr[0][0], b0, a0, 0, 0, 0);
    a0 = __builtin_amdgcn_mfma_f32_16x16x32_bf16(afr[0][1], b1, a0, 0, 0, 0);
    a1 = __builtin_amdgcn_mfma_f32_16x16x32_bf16(afr[1][0], b0, a1, 0, 0, 0);
    a1 = __builtin_amdgcn_mfma_f32_16x16x32_bf16(afr[1][1], b1, a1, 0, 0, 0);
#pragma unroll
    for (int r = 0; r < 4; ++r) {
      ao[((c0 + kg * 4 + r) << 7) + dt * 16 + col] = fmaxf(a0[r], 0.f);
      ao[((c0 + 16 + kg * 4 + r) << 7) + dt * 16 + col] = fmaxf(a1[r], 0.f);
    }
  }
}

// =======================================================================
// Kernel 2b: dw(v) + out = V * attn via bf16 MFMA.
// a_t stride 40 shorts = 80 B (16B-multiple for b128; 2-way banks = free).
// =======================================================================
__global__ __launch_bounds__(256) void k_pv(const __hip_bfloat16* __restrict__ qkv,
                                            const float* __restrict__ wdw,
                                            const float* __restrict__ attn,
                                            __hip_bfloat16* __restrict__ out_win) {
  __shared__ unsigned short halo_s[128 * 124];
  __shared__ unsigned short v_t[64][136];   // [p][c] bf16 (272 B stride)
  __shared__ unsigned short a_t[128][40];   // [d][c-chunk 32] bf16 (80 B stride)

  int blk = blockIdx.x;
  int b = blk >> 10, n = blk & 1023;
  int ih0 = (n >> 5) << 3, iw0 = (n & 31) << 3;
  int t = threadIdx.x;
  int ch_l = t & 15, pq = t >> 4;

  {
    const __hip_bfloat16* base = qkv + (((size_t)((2 * NB + b) * CC)) << 16);
#pragma unroll 1
    for (int i = 0; i < 50; ++i) {
      int idx = i * 256 + t;
      int ch = idx / 100;
      int pos = idx - ch * 100;
      int r = pos / 10, cl = pos - r * 10;
      int ii = ih0 - 1 + r, jj = iw0 - 1 + cl;
      unsigned short hv = 0;
      if ((unsigned)ii < 256u && (unsigned)jj < 256u)
        hv = __builtin_bit_cast(unsigned short,
                                base[((size_t)ch << 16) + (ii << 8) + jj]);
      halo_s[ch * 124 + r * 12 + cl] = hv;
    }
  }
  __syncthreads();
#pragma unroll 1
  for (int ch_hi = 0; ch_hi < 8; ++ch_hi) {
    int ch = ch_hi * 16 + ch_l;
    float wd[9];
#pragma unroll
    for (int kk = 0; kk < 9; ++kk) wd[kk] = wdw[(2 * CC + ch) * 9 + kk];
    const unsigned short* hb = &halo_s[ch * 124];
#pragma unroll
    for (int u = 0; u < 4; ++u) {
      int px = pq + (u << 4);
      int pr = px >> 3, pc = px & 7;
      float v = 0.f;
#pragma unroll
      for (int r = 0; r < 3; ++r)
#pragma unroll
        for (int s = 0; s < 3; ++s)
          v = fmaf(wd[r * 3 + s], bf2f(hb[(pr + r) * 12 + pc + s]), v);
      v_t[px][ch] = f2bf(v);           // [p][c] layout (stride 136 — correct)
    }
  }

  // out[p][d] = sum_c v[p][c] * attn[c][d]; wave wv owns p-tile wv (16 p).
  int wv = t >> 6, lane = t & 63;
  int col = lane & 15, kg = lane >> 4;
  f32x4 acc[8];
#pragma unroll
  for (int dt = 0; dt < 8; ++dt) acc[dt] = {0.f, 0.f, 0.f, 0.f};
  const float* ab = attn + ((size_t)blk << 14);
#pragma unroll 1
  for (int ks = 0; ks < 4; ++ks) {
    __syncthreads();                  // v_t ready (ks=0) / prev a_t reads done
    // stage+transpose attn[ks*32..+31][0..127] fp32 -> a_t[d][c] bf16
#pragma unroll
    for (int it = 0; it < 2; ++it) {
      int idx = it * 256 + t;
      int d4 = idx & 31, cp = idx >> 5;    // cp 0..15 (c-pair)
      const float* ar = ab + (((size_t)(ks * 32 + cp * 2)) << 7) + d4 * 4;
      float4 r0 = *(const float4*)ar;
      float4 r1 = *(const float4*)(ar + 128);
      float a0a[4] = {r0.x, r0.y, r0.z, r0.w};
      float a1a[4] = {r1.x, r1.y, r1.z, r1.w};
#pragma unroll
      for (int e = 0; e < 4; ++e) {
        unsigned pk = (unsigned)f2bf(a0a[e]) | ((unsigned)f2bf(a1a[e]) << 16);
        *(unsigned*)&a_t[d4 * 4 + e][cp * 2] = pk;
      }
    }
    __syncthreads();
    bf16x8 va = *(const bf16x8*)&v_t[wv * 16 + col][ks * 32 + kg * 8];
#pragma unroll
    for (int dt = 0; dt < 8; ++dt) {
      bf16x8 bf = *(const bf16x8*)&a_t[dt * 16 + col][kg * 8];
      acc[dt] = __builtin_amdgcn_mfma_f32_16x16x32_bf16(va, bf, acc[dt], 0, 0, 0);
    }
  }
  __hip_bfloat16* ow = out_win + ((size_t)blk << 13);   // 64*128 per window
#pragma unroll
  for (int dt = 0; dt < 8; ++dt)
#pragma unroll
    for (int r = 0; r < 4; ++r)
      ow[((wv * 16 + kg * 4 + r) << 7) + dt * 16 + col] = __float2bfloat16(acc[dt][r]);
}

// =======================================================================
// Kernel 3: proj 1x1 as bf16 MFMA GEMM (unchanged from round 3).
// =======================================================================
__global__ __launch_bounds__(256) void k_proj_mfma(const __hip_bfloat16* __restrict__ out_win,
                                                   const float* __restrict__ wp,
                                                   float* __restrict__ y) {
  __shared__ unsigned short w_s[128 * 136];   // [och][c] bf16

  int t = threadIdx.x;
  {
    int och = t >> 1, ch0 = (t & 1) << 6;
    const float* wr = wp + och * CC + ch0;
#pragma unroll
    for (int u = 0; u < 32; ++u) {
      float2 v = *(const float2*)(wr + 2 * u);
      unsigned pk = (unsigned)f2bf(v.x) | ((unsigned)f2bf(v.y) << 16);
      *(unsigned*)&w_s[och * 136 + ch0 + 2 * u] = pk;
    }
  }
  __syncthreads();

  int w = t >> 6, lane = t & 63;
  int col = lane & 15, kg = lane >> 4;
  int bn = blockIdx.x * 4 + w;
  int b = bn >> 10, n = bn & 1023;
  const __hip_bfloat16* ob = out_win + ((size_t)bn << 13);

  bf16x8 afr[8][4];
#pragma unroll
  for (int mt = 0; mt < 8; ++mt)
#pragma unroll
    for (int ks = 0; ks < 4; ++ks)
      afr[mt][ks] = *(const bf16x8*)&w_s[(mt * 16 + col) * 136 + ks * 32 + kg * 8];

#pragma unroll 1
  for (int nt = 0; nt < 4; ++nt) {
    int p = nt * 16 + col;
    bf16x8 bfr[4];
#pragma unroll
    for (int ks = 0; ks < 4; ++ks)
      bfr[ks] = *(const bf16x8*)(ob + p * CC + ks * 32 + kg * 8);
    int i_f = (((n >> 5) << 3) + (p >> 3) + 4) & 255;
    int j_f = (((n & 31) << 3) + (p & 7) + 4) & 255;
    float* yp = y + (((size_t)b * CC) << 16) + (i_f << 8) + j_f;
#pragma unroll
    for (int mt = 0; mt < 8; ++mt) {
      f32x4 acc = {0.f, 0.f, 0.f, 0.f};
#pragma unroll
      for (int ks = 0; ks < 4; ++ks)
        acc = __builtin_amdgcn_mfma_f32_16x16x32_bf16(afr[mt][ks], bfr[ks], acc, 0, 0, 0);
#pragma unroll
      for (int r = 0; r < 4; ++r) {
        int och = mt * 16 + kg * 4 + r;
        yp[(size_t)och << 16] = acc[r];
      }
    }
  }
}

extern "C" void kernel_launch(void* const* d_in, const int* in_sizes, int n_in,
                              void* d_out, int out_size, void* d_ws, size_t ws_size,
                              hipStream_t stream) {
  const float* x = (const float*)d_in[0];
  const float* w_qkv = (const float*)d_in[1];
  const float* w_dw = (const float*)d_in[2];
  const float* w_proj = (const float*)d_in[3];
  const float* temp = (const float*)d_in[4];
  float* y = (float*)d_out;
  float* attn = (float*)d_out + (size_t)NB * CC * HW;   // y first, then attn

  // d_ws (bf16): qkv [3][b][c][hw] = 201 MB; out_win (67 MB) reuses the q
  // region (dead after k_attn; disjoint from v region read by k_pv).
  __hip_bfloat16* qkv = (__hip_bfloat16*)d_ws;
  __hip_bfloat16* out_win = (__hip_bfloat16*)d_ws;

  k_qkv_mfma<<<2048, 256, 0, stream>>>(x, w_qkv, qkv);
  k_attn<<<4096, 256, 0, stream>>>(qkv, w_dw, temp, attn);
  k_pv<<<4096, 256, 0, stream>>>(qkv, w_dw, attn, out_win);
  k_proj_mfma<<<1024, 256, 0, stream>>>(out_win, w_proj, y);
}

// Round 7
// 753.559 us; speedup vs baseline: 10.9035x; 1.5921x over previous
//
#include <hip/hip_runtime.h>
#include <hip/hip_bf16.h>

// Problem constants
constexpr int NB = 4;        // batch
constexpr int CC = 128;      // channels
constexpr int HW = 65536;    // 256*256 pixels per (b, channel) plane
// windows: 32x32 = 1024 per batch, 8x8 = 64 px per window

using bf16x8 = __attribute__((ext_vector_type(8))) short;   // MFMA A/B frag (4 VGPR)
using f32x4  = __attribute__((ext_vector_type(4))) float;   // MFMA C/D frag

__device__ __forceinline__ unsigned short f2bf(float f) {
  unsigned u = __builtin_bit_cast(unsigned, f);
  u += 0x7FFFu + ((u >> 16) & 1u);
  return (unsigned short)(u >> 16);
}
__device__ __forceinline__ float bf2f(unsigned short s) {
  return __builtin_bit_cast(float, (unsigned)s << 16);
}

// Halo LDS layout: halo[ch*168 + r*16 + slot], r = 0..9 (image row ih0-1+r).
// slot 0..7 = window px (j = iw0..iw0+7), slot 8 = right halo (j = iw0+8),
// slot 9 = left halo (j = iw0-1). Channel stride 168 shorts = 336 B -> 2-way
// bank pattern on 16-lane b128 reads (free, m136).
__device__ __forceinline__ void stage_halo_vec(const __hip_bfloat16* __restrict__ base,
                                               int ih0, int iw0, int t,
                                               unsigned short* __restrict__ halo) {
  // 128 ch x 10 r x 3 chunks = 3840 tasks; chunk c covers j = iw0-8+8c .. +7.
#pragma unroll
  for (int it = 0; it < 15; ++it) {
    int idx = it * 256 + t;
    int ch = idx / 30;
    int rem = idx - ch * 30;
    int r = rem / 3;
    int c = rem - r * 3;
    int ii = ih0 - 1 + r;
    int j0 = iw0 - 8 + c * 8;
    uint4 v = {0u, 0u, 0u, 0u};
    if ((unsigned)ii < 256u && (unsigned)j0 <= 248u)
      v = *(const uint4*)(base + (((size_t)ch) << 16) + (ii << 8) + j0);
    unsigned short* hrow = halo + ch * 168 + r * 16;
    if (c == 1) {
      *(uint4*)hrow = v;                               // window px 0..7
    } else if (c == 0) {
      hrow[9] = (unsigned short)(v.w >> 16);           // left halo (j=iw0-1)
    } else {
      hrow[8] = (unsigned short)(v.x & 0xFFFFu);       // right halo (j=iw0+8)
    }
  }
}

// dw 3x3 for one (ch, pr) output row of 8 px; halo row reads are b128 + 2 scalars.
__device__ __forceinline__ void dw_row(const unsigned short* __restrict__ halo,
                                       const float* __restrict__ wd,
                                       int ch, int pr, float* __restrict__ outv) {
#pragma unroll
  for (int pc = 0; pc < 8; ++pc) outv[pc] = 0.f;
#pragma unroll
  for (int kr = 0; kr < 3; ++kr) {
    const unsigned short* hrow = halo + ch * 168 + (pr + kr) * 16;
    uint4 rw = *(const uint4*)hrow;
    float rv[10];
    rv[0] = bf2f((unsigned short)(rw.x & 0xFFFFu));
    rv[1] = bf2f((unsigned short)(rw.x >> 16));
    rv[2] = bf2f((unsigned short)(rw.y & 0xFFFFu));
    rv[3] = bf2f((unsigned short)(rw.y >> 16));
    rv[4] = bf2f((unsigned short)(rw.z & 0xFFFFu));
    rv[5] = bf2f((unsigned short)(rw.z >> 16));
    rv[6] = bf2f((unsigned short)(rw.w & 0xFFFFu));
    rv[7] = bf2f((unsigned short)(rw.w >> 16));
    rv[8] = bf2f(hrow[8]);   // right
    rv[9] = bf2f(hrow[9]);   // left
#pragma unroll
    for (int s = 0; s < 3; ++s) {
      float wv = wd[kr * 3 + s];
#pragma unroll
      for (int pc = 0; pc < 8; ++pc) {
        int m = pc + s - 1;                 // -1..8, compile-time after unroll
        float xv = (m < 0) ? rv[9] : rv[m]; // m==8 -> rv[8] = right halo
        outv[pc] = fmaf(wv, xv, outv[pc]);
      }
    }
  }
}

// =======================================================================
// Kernel 1: rolled 1x1 conv as bf16 MFMA GEMM (unchanged, verified).
// =======================================================================
__global__ __launch_bounds__(256) void k_qkv_mfma(const float* __restrict__ x,
                                                  const float* __restrict__ wq,
                                                  __hip_bfloat16* __restrict__ qkv) {
  __shared__ unsigned short x_s[128 * 136];   // [px][c]

  int blk = blockIdx.x;                 // 4 b x 256 i x 2 j-half
  int b = blk >> 9, i = (blk >> 1) & 255, jh = blk & 1;
  int j0 = jh << 7;
  int si = (i + 4) & 255;               // roll(-4): source row
  int t = threadIdx.x;

  {
    int c0 = (t & 63) << 1;             // channel pair
    int jb = (t >> 6) << 5;             // 32-px strip
    const float* xr0 = x + (((size_t)(b * CC + c0)) << 16) + (si << 8);
    const float* xr1 = xr0 + HW;
#pragma unroll
    for (int u = 0; u < 8; ++u) {
      int jj = jb + (u << 2);
      int sj = j0 + jj + 4;
      float v0[4], v1[4];
      if (sj + 3 <= 255) {
        *(float4*)v0 = *(const float4*)(xr0 + sj);
        *(float4*)v1 = *(const float4*)(xr1 + sj);
      } else {
#pragma unroll
        for (int e = 0; e < 4; ++e) {
          int s = (sj + e) & 255;
          v0[e] = xr0[s];
          v1[e] = xr1[s];
        }
      }
#pragma unroll
      for (int e = 0; e < 4; ++e) {
        unsigned pk = (unsigned)f2bf(v0[e]) | ((unsigned)f2bf(v1[e]) << 16);
        *(unsigned*)&x_s[(jj + e) * 136 + c0] = pk;
      }
    }
  }
  __syncthreads();

  int w = t >> 6;
  int lane = t & 63;
  int col = lane & 15;
  int kg = lane >> 4;

#pragma unroll 1
  for (int oi = 0; oi < 3; ++oi) {
    int m0 = oi * 128 + w * 32;
    bf16x8 afr[2][4];
#pragma unroll
    for (int mt = 0; mt < 2; ++mt) {
      const float* wr = wq + (m0 + mt * 16 + col) * CC + kg * 8;
#pragma unroll
      for (int ks = 0; ks < 4; ++ks) {
        float wa[4], wb[4];
        *(float4*)wa = *(const float4*)(wr + ks * 32);
        *(float4*)wb = *(const float4*)(wr + ks * 32 + 4);
        bf16x8 f;
#pragma unroll
        for (int e = 0; e < 4; ++e) {
          f[e] = (short)f2bf(wa[e]);
          f[e + 4] = (short)f2bf(wb[e]);
        }
        afr[mt][ks] = f;
      }
    }
#pragma unroll 1
    for (int n = 0; n < 8; ++n) {
      int px = n * 16 + col;
      f32x4 acc0 = {0.f, 0.f, 0.f, 0.f};
      f32x4 acc1 = {0.f, 0.f, 0.f, 0.f};
#pragma unroll
      for (int ks = 0; ks < 4; ++ks) {
        bf16x8 bfr = *(const bf16x8*)&x_s[px * 136 + ks * 32 + kg * 8];
        acc0 = __builtin_amdgcn_mfma_f32_16x16x32_bf16(afr[0][ks], bfr, acc0, 0, 0, 0);
        acc1 = __builtin_amdgcn_mfma_f32_16x16x32_bf16(afr[1][ks], bfr, acc1, 0, 0, 0);
      }
      int j = j0 + n * 16 + col;
#pragma unroll
      for (int r = 0; r < 4; ++r) {
        int och0 = m0 + kg * 4 + r;
        int och1 = m0 + 16 + kg * 4 + r;
        int g0 = och0 >> 7, c0 = och0 & 127;
        int g1 = och1 >> 7, c1 = och1 & 127;
        qkv[(((size_t)((g0 * NB + b) * CC + c0)) << 16) + (i << 8) + j] =
            __float2bfloat16(acc0[r]);
        qkv[(((size_t)((g1 * NB + b) * CC + c1)) << 16) + (i << 8) + j] =
            __float2bfloat16(acc1[r]);
      }
    }
  }
}

// =======================================================================
// Kernel 2a: dw(q,k) + normalize + attn = relu(tau * Q^T K) via bf16 MFMA.
// Round-7: vectorized halo staging (15 uint4 loads/thread) + row-based dw
// (9 LDS ops per output row vs 72 scalar) + in-register scaling.
// LDS 80.4 KB -> 2 blocks/CU.
// =======================================================================
__global__ __launch_bounds__(256) void k_attn(const __hip_bfloat16* __restrict__ qkv,
                                              const float* __restrict__ wdw,
                                              const float* __restrict__ temp_p,
                                              float* __restrict__ attn_out) {
  __shared__ unsigned short halo_s[128 * 168];   // 43008 B
  __shared__ unsigned short q_t[128][72];        // [c][p] bf16 (144 B stride)
  __shared__ unsigned short k_t[128][72];
  __shared__ float sumsq_s[64];
  __shared__ float ps[64];

  int blk = blockIdx.x;              // b*1024 + n
  int b = blk >> 10, n = blk & 1023;
  int ih0 = (n >> 5) << 3, iw0 = (n & 31) << 3;
  int t = threadIdx.x;
  int ch_l = t & 15, grp = t >> 4;   // 16 lanes of a group = 16 consecutive ch
  float tau = temp_p[0];

#pragma unroll 1
  for (int g = 0; g < 2; ++g) {      // 0 = q, 1 = k
    __syncthreads();                 // halo_s / sumsq reuse safe
    if (t < 64) sumsq_s[t] = 0.f;
    stage_halo_vec(qkv + (((size_t)((g * NB + b) * CC)) << 16), ih0, iw0, t, halo_s);
    __syncthreads();

    float outv[4][8];                // 4 (ch,row) tasks x 8 px, lives across barrier
#pragma unroll
    for (int it = 0; it < 4; ++it) {
      int task = grp + it * 16;      // 0..63
      int ch = ((task >> 3) << 4) + ch_l;
      int pr = task & 7;
      float wd[9];
#pragma unroll
      for (int kk = 0; kk < 9; ++kk) wd[kk] = wdw[(g * CC + ch) * 9 + kk];
      dw_row(halo_s, wd, ch, pr, outv[it]);
      // per-pixel sumsq over channels: 16-lane shfl + atomic over ch_hi groups
#pragma unroll
      for (int pc = 0; pc < 8; ++pc) {
        float sq = outv[it][pc] * outv[it][pc];
        sq += __shfl_xor(sq, 1);
        sq += __shfl_xor(sq, 2);
        sq += __shfl_xor(sq, 4);
        sq += __shfl_xor(sq, 8);
        if (ch_l == 0) atomicAdd(&sumsq_s[pr * 8 + pc], sq);
      }
    }
    __syncthreads();
    if (t < 64) {
      float nr = fmaxf(sqrtf(sumsq_s[t]), 1e-12f);
      ps[t] = g ? (tau / nr) : (1.f / nr);   // tau folded into k's scale
    }
    __syncthreads();
    unsigned short (*dst)[72] = g ? k_t : q_t;
#pragma unroll
    for (int it = 0; it < 4; ++it) {
      int task = grp + it * 16;
      int ch = ((task >> 3) << 4) + ch_l;
      int pr = task & 7;
      unsigned short o8[8];
#pragma unroll
      for (int pc = 0; pc < 8; ++pc)
        o8[pc] = f2bf(outv[it][pc] * ps[pr * 8 + pc]);
      *(uint4*)&dst[ch][pr * 8] = *(const uint4*)o8;   // [c][p], b128 write
    }
  }
  __syncthreads();

  // attn[c][d] = sum_p q_t[c][p] * k_t[d][p]; wave wv owns c-band wv*32..+31.
  int wv = t >> 6, lane = t & 63;
  int col = lane & 15, kg = lane >> 4;
  int c0 = wv * 32;
  bf16x8 afr[2][2];
#pragma unroll
  for (int mt = 0; mt < 2; ++mt)
#pragma unroll
    for (int ks = 0; ks < 2; ++ks)
      afr[mt][ks] = *(const bf16x8*)&q_t[c0 + mt * 16 + col][ks * 32 + kg * 8];
  float* ao = attn_out + ((size_t)blk << 14);   // 128*128 per window
#pragma unroll
  for (int dt = 0; dt < 8; ++dt) {
    bf16x8 b0 = *(const bf16x8*)&k_t[dt * 16 + col][kg * 8];
    bf16x8 b1 = *(const bf16x8*)&k_t[dt * 16 + col][32 + kg * 8];
    f32x4 a0 = {0.f, 0.f, 0.f, 0.f};
    f32x4 a1 = {0.f, 0.f, 0.f, 0.f};
    a0 = __builtin_amdgcn_mfma_f32_16x16x32_bf16(afr[0][0], b0, a0, 0, 0, 0);
    a0 = __builtin_amdgcn_mfma_f32_16x16x32_bf16(afr[0][1], b1, a0, 0, 0, 0);
    a1 = __builtin_amdgcn_mfma_f32_16x16x32_bf16(afr[1][0], b0, a1, 0, 0, 0);
    a1 = __builtin_amdgcn_mfma_f32_16x16x32_bf16(afr[1][1], b1, a1, 0, 0, 0);
#pragma unroll
    for (int r = 0; r < 4; ++r) {
      ao[((c0 + kg * 4 + r) << 7) + dt * 16 + col] = fmaxf(a0[r], 0.f);
      ao[((c0 + 16 + kg * 4 + r) << 7) + dt * 16 + col] = fmaxf(a1[r], 0.f);
    }
  }
}

// =======================================================================
// Kernel 2b: dw(v) + out = V * attn via bf16 MFMA. Round-7 staging/dw.
// =======================================================================
__global__ __launch_bounds__(256) void k_pv(const __hip_bfloat16* __restrict__ qkv,
                                            const float* __restrict__ wdw,
                                            const float* __restrict__ attn,
                                            __hip_bfloat16* __restrict__ out_win) {
  __shared__ unsigned short halo_s[128 * 168];
  __shared__ unsigned short v_t[64][136];   // [p][c] bf16 (272 B stride)
  __shared__ unsigned short a_t[128][40];   // [d][c-chunk 32] bf16 (80 B stride)

  int blk = blockIdx.x;
  int b = blk >> 10, n = blk & 1023;
  int ih0 = (n >> 5) << 3, iw0 = (n & 31) << 3;
  int t = threadIdx.x;
  int ch_l = t & 15, grp = t >> 4;

  stage_halo_vec(qkv + (((size_t)((2 * NB + b) * CC)) << 16), ih0, iw0, t, halo_s);
  __syncthreads();
#pragma unroll
  for (int it = 0; it < 4; ++it) {
    int task = grp + it * 16;
    int ch = ((task >> 3) << 4) + ch_l;
    int pr = task & 7;
    float wd[9];
#pragma unroll
    for (int kk = 0; kk < 9; ++kk) wd[kk] = wdw[(2 * CC + ch) * 9 + kk];
    float outv[8];
    dw_row(halo_s, wd, ch, pr, outv);
#pragma unroll
    for (int pc = 0; pc < 8; ++pc)
      v_t[pr * 8 + pc][ch] = f2bf(outv[pc]);   // [p][c]
  }

  // out[p][d] = sum_c v[p][c] * attn[c][d]; wave wv owns p-tile wv (16 p).
  int wv = t >> 6, lane = t & 63;
  int col = lane & 15, kg = lane >> 4;
  f32x4 acc[8];
#pragma unroll
  for (int dt = 0; dt < 8; ++dt) acc[dt] = {0.f, 0.f, 0.f, 0.f};
  const float* ab = attn + ((size_t)blk << 14);
#pragma unroll 1
  for (int ks = 0; ks < 4; ++ks) {
    __syncthreads();                  // v_t ready (ks=0) / prev a_t reads done
    // stage+transpose attn[ks*32..+31][0..127] fp32 -> a_t[d][c] bf16
#pragma unroll
    for (int it = 0; it < 2; ++it) {
      int idx = it * 256 + t;
      int d4 = idx & 31, cp = idx >> 5;    // cp 0..15 (c-pair)
      const float* ar = ab + (((size_t)(ks * 32 + cp * 2)) << 7) + d4 * 4;
      float4 r0 = *(const float4*)ar;
      float4 r1 = *(const float4*)(ar + 128);
      float a0a[4] = {r0.x, r0.y, r0.z, r0.w};
      float a1a[4] = {r1.x, r1.y, r1.z, r1.w};
#pragma unroll
      for (int e = 0; e < 4; ++e) {
        unsigned pk = (unsigned)f2bf(a0a[e]) | ((unsigned)f2bf(a1a[e]) << 16);
        *(unsigned*)&a_t[d4 * 4 + e][cp * 2] = pk;
      }
    }
    __syncthreads();
    bf16x8 va = *(const bf16x8*)&v_t[wv * 16 + col][ks * 32 + kg * 8];
#pragma unroll
    for (int dt = 0; dt < 8; ++dt) {
      bf16x8 bf = *(const bf16x8*)&a_t[dt * 16 + col][kg * 8];
      acc[dt] = __builtin_amdgcn_mfma_f32_16x16x32_bf16(va, bf, acc[dt], 0, 0, 0);
    }
  }
  __hip_bfloat16* ow = out_win + ((size_t)blk << 13);   // 64*128 per window
#pragma unroll
  for (int dt = 0; dt < 8; ++dt)
#pragma unroll
    for (int r = 0; r < 4; ++r)
      ow[((wv * 16 + kg * 4 + r) << 7) + dt * 16 + col] = __float2bfloat16(acc[dt][r]);
}

// =======================================================================
// Kernel 3: proj 1x1 as bf16 MFMA GEMM (unchanged, verified).
// =======================================================================
__global__ __launch_bounds__(256) void k_proj_mfma(const __hip_bfloat16* __restrict__ out_win,
                                                   const float* __restrict__ wp,
                                                   float* __restrict__ y) {
  __shared__ unsigned short w_s[128 * 136];   // [och][c] bf16

  int t = threadIdx.x;
  {
    int och = t >> 1, ch0 = (t & 1) << 6;
    const float* wr = wp + och * CC + ch0;
#pragma unroll
    for (int u = 0; u < 32; ++u) {
      float2 v = *(const float2*)(wr + 2 * u);
      unsigned pk = (unsigned)f2bf(v.x) | ((unsigned)f2bf(v.y) << 16);
      *(unsigned*)&w_s[och * 136 + ch0 + 2 * u] = pk;
    }
  }
  __syncthreads();

  int w = t >> 6, lane = t & 63;
  int col = lane & 15, kg = lane >> 4;
  int bn = blockIdx.x * 4 + w;
  int b = bn >> 10, n = bn & 1023;
  const __hip_bfloat16* ob = out_win + ((size_t)bn << 13);

  bf16x8 afr[8][4];
#pragma unroll
  for (int mt = 0; mt < 8; ++mt)
#pragma unroll
    for (int ks = 0; ks < 4; ++ks)
      afr[mt][ks] = *(const bf16x8*)&w_s[(mt * 16 + col) * 136 + ks * 32 + kg * 8];

#pragma unroll 1
  for (int nt = 0; nt < 4; ++nt) {
    int p = nt * 16 + col;
    bf16x8 bfr[4];
#pragma unroll
    for (int ks = 0; ks < 4; ++ks)
      bfr[ks] = *(const bf16x8*)(ob + p * CC + ks * 32 + kg * 8);
    int i_f = (((n >> 5) << 3) + (p >> 3) + 4) & 255;
    int j_f = (((n & 31) << 3) + (p & 7) + 4) & 255;
    float* yp = y + (((size_t)b * CC) << 16) + (i_f << 8) + j_f;
#pragma unroll
    for (int mt = 0; mt < 8; ++mt) {
      f32x4 acc = {0.f, 0.f, 0.f, 0.f};
#pragma unroll
      for (int ks = 0; ks < 4; ++ks)
        acc = __builtin_amdgcn_mfma_f32_16x16x32_bf16(afr[mt][ks], bfr[ks], acc, 0, 0, 0);
#pragma unroll
      for (int r = 0; r < 4; ++r) {
        int och = mt * 16 + kg * 4 + r;
        yp[(size_t)och << 16] = acc[r];
      }
    }
  }
}

extern "C" void kernel_launch(void* const* d_in, const int* in_sizes, int n_in,
                              void* d_out, int out_size, void* d_ws, size_t ws_size,
                              hipStream_t stream) {
  const float* x = (const float*)d_in[0];
  const float* w_qkv = (const float*)d_in[1];
  const float* w_dw = (const float*)d_in[2];
  const float* w_proj = (const float*)d_in[3];
  const float* temp = (const float*)d_in[4];
  float* y = (float*)d_out;
  float* attn = (float*)d_out + (size_t)NB * CC * HW;   // y first, then attn

  // d_ws (bf16): qkv [3][b][c][hw] = 201 MB; out_win (67 MB) reuses the q
  // region (dead after k_attn; disjoint from v region read by k_pv).
  __hip_bfloat16* qkv = (__hip_bfloat16*)d_ws;
  __hip_bfloat16* out_win = (__hip_bfloat16*)d_ws;

  k_qkv_mfma<<<2048, 256, 0, stream>>>(x, w_qkv, qkv);
  k_attn<<<4096, 256, 0, stream>>>(qkv, w_dw, temp, attn);
  k_pv<<<4096, 256, 0, stream>>>(qkv, w_dw, attn, out_win);
  k_proj_mfma<<<1024, 256, 0, stream>>>(out_win, w_proj, y);
}

// Round 8
// 676.813 us; speedup vs baseline: 12.1399x; 1.1134x over previous
//
#include <hip/hip_runtime.h>
#include <hip/hip_bf16.h>

// Problem constants
constexpr int NB = 4;        // batch
constexpr int CC = 128;      // channels
constexpr int HW = 65536;    // 256*256 pixels per (b, channel) plane
// windows: 32x32 = 1024 per batch, 8x8 = 64 px per window

using bf16x8 = __attribute__((ext_vector_type(8))) short;   // MFMA A/B frag (4 VGPR)
using f32x4  = __attribute__((ext_vector_type(4))) float;   // MFMA C/D frag

__device__ __forceinline__ unsigned short f2bf(float f) {
  unsigned u = __builtin_bit_cast(unsigned, f);
  u += 0x7FFFu + ((u >> 16) & 1u);
  return (unsigned short)(u >> 16);
}
__device__ __forceinline__ float bf2f(unsigned short s) {
  return __builtin_bit_cast(float, (unsigned)s << 16);
}

// Halo LDS layout: halo[ch*168 + r*16 + slot], r = 0..9 (image row ih0-1+r).
// slot 0..7 = window px, slot 8 = right halo, 9 = left halo. ch stride 336 B
// -> 2-way bank pattern on 16-lane reads (free).
__device__ __forceinline__ void halo_decomp(int idx, int& ch, int& r, int& c) {
  ch = idx / 30;
  int rem = idx - ch * 30;
  r = rem / 3;
  c = rem - r * 3;
}
__device__ __forceinline__ uint4 halo_load_one(const __hip_bfloat16* __restrict__ base,
                                               int ih0, int iw0, int idx) {
  int ch, r, c;
  halo_decomp(idx, ch, r, c);
  int ii = ih0 - 1 + r, j0 = iw0 - 8 + c * 8;
  uint4 v = {0u, 0u, 0u, 0u};
  if ((unsigned)ii < 256u && (unsigned)j0 <= 248u)
    v = *(const uint4*)(base + (((size_t)ch) << 16) + (ii << 8) + j0);
  return v;
}
__device__ __forceinline__ void halo_store_one(unsigned short* __restrict__ halo,
                                               int idx, uint4 v) {
  int ch, r, c;
  halo_decomp(idx, ch, r, c);
  unsigned short* hrow = halo + ch * 168 + r * 16;
  if (c == 1) *(uint4*)hrow = v;
  else if (c == 0) hrow[9] = (unsigned short)(v.w >> 16);
  else hrow[8] = (unsigned short)(v.x & 0xFFFFu);
}

// dw 3x3 for one (ch, pr) output row of 8 px.
__device__ __forceinline__ void dw_row(const unsigned short* __restrict__ halo,
                                       const float* __restrict__ wd,
                                       int ch, int pr, float* __restrict__ outv) {
#pragma unroll
  for (int pc = 0; pc < 8; ++pc) outv[pc] = 0.f;
#pragma unroll
  for (int kr = 0; kr < 3; ++kr) {
    const unsigned short* hrow = halo + ch * 168 + (pr + kr) * 16;
    uint4 rw = *(const uint4*)hrow;
    float rv[10];
    rv[0] = bf2f((unsigned short)(rw.x & 0xFFFFu));
    rv[1] = bf2f((unsigned short)(rw.x >> 16));
    rv[2] = bf2f((unsigned short)(rw.y & 0xFFFFu));
    rv[3] = bf2f((unsigned short)(rw.y >> 16));
    rv[4] = bf2f((unsigned short)(rw.z & 0xFFFFu));
    rv[5] = bf2f((unsigned short)(rw.z >> 16));
    rv[6] = bf2f((unsigned short)(rw.w & 0xFFFFu));
    rv[7] = bf2f((unsigned short)(rw.w >> 16));
    rv[8] = bf2f(hrow[8]);   // right
    rv[9] = bf2f(hrow[9]);   // left
#pragma unroll
    for (int s = 0; s < 3; ++s) {
      float wv = wd[kr * 3 + s];
#pragma unroll
      for (int pc = 0; pc < 8; ++pc) {
        int m = pc + s - 1;
        float xv = (m < 0) ? rv[9] : rv[m];
        outv[pc] = fmaf(wv, xv, outv[pc]);
      }
    }
  }
}

// =======================================================================
// Kernel 1: rolled 1x1 conv as bf16 MFMA GEMM (unchanged, verified).
// =======================================================================
__global__ __launch_bounds__(256) void k_qkv_mfma(const float* __restrict__ x,
                                                  const float* __restrict__ wq,
                                                  __hip_bfloat16* __restrict__ qkv) {
  __shared__ unsigned short x_s[128 * 136];   // [px][c]

  int blk = blockIdx.x;                 // 4 b x 256 i x 2 j-half
  int b = blk >> 9, i = (blk >> 1) & 255, jh = blk & 1;
  int j0 = jh << 7;
  int si = (i + 4) & 255;               // roll(-4): source row
  int t = threadIdx.x;

  {
    int c0 = (t & 63) << 1;
    int jb = (t >> 6) << 5;
    const float* xr0 = x + (((size_t)(b * CC + c0)) << 16) + (si << 8);
    const float* xr1 = xr0 + HW;
#pragma unroll
    for (int u = 0; u < 8; ++u) {
      int jj = jb + (u << 2);
      int sj = j0 + jj + 4;
      float v0[4], v1[4];
      if (sj + 3 <= 255) {
        *(float4*)v0 = *(const float4*)(xr0 + sj);
        *(float4*)v1 = *(const float4*)(xr1 + sj);
      } else {
#pragma unroll
        for (int e = 0; e < 4; ++e) {
          int s = (sj + e) & 255;
          v0[e] = xr0[s];
          v1[e] = xr1[s];
        }
      }
#pragma unroll
      for (int e = 0; e < 4; ++e) {
        unsigned pk = (unsigned)f2bf(v0[e]) | ((unsigned)f2bf(v1[e]) << 16);
        *(unsigned*)&x_s[(jj + e) * 136 + c0] = pk;
      }
    }
  }
  __syncthreads();

  int w = t >> 6;
  int lane = t & 63;
  int col = lane & 15;
  int kg = lane >> 4;

#pragma unroll 1
  for (int oi = 0; oi < 3; ++oi) {
    int m0 = oi * 128 + w * 32;
    bf16x8 afr[2][4];
#pragma unroll
    for (int mt = 0; mt < 2; ++mt) {
      const float* wr = wq + (m0 + mt * 16 + col) * CC + kg * 8;
#pragma unroll
      for (int ks = 0; ks < 4; ++ks) {
        float wa[4], wb[4];
        *(float4*)wa = *(const float4*)(wr + ks * 32);
        *(float4*)wb = *(const float4*)(wr + ks * 32 + 4);
        bf16x8 f;
#pragma unroll
        for (int e = 0; e < 4; ++e) {
          f[e] = (short)f2bf(wa[e]);
          f[e + 4] = (short)f2bf(wb[e]);
        }
        afr[mt][ks] = f;
      }
    }
#pragma unroll 1
    for (int n = 0; n < 8; ++n) {
      int px = n * 16 + col;
      f32x4 acc0 = {0.f, 0.f, 0.f, 0.f};
      f32x4 acc1 = {0.f, 0.f, 0.f, 0.f};
#pragma unroll
      for (int ks = 0; ks < 4; ++ks) {
        bf16x8 bfr = *(const bf16x8*)&x_s[px * 136 + ks * 32 + kg * 8];
        acc0 = __builtin_amdgcn_mfma_f32_16x16x32_bf16(afr[0][ks], bfr, acc0, 0, 0, 0);
        acc1 = __builtin_amdgcn_mfma_f32_16x16x32_bf16(afr[1][ks], bfr, acc1, 0, 0, 0);
      }
      int j = j0 + n * 16 + col;
#pragma unroll
      for (int r = 0; r < 4; ++r) {
        int och0 = m0 + kg * 4 + r;
        int och1 = m0 + 16 + kg * 4 + r;
        int g0 = och0 >> 7, c0 = och0 & 127;
        int g1 = och1 >> 7, c1 = och1 & 127;
        qkv[(((size_t)((g0 * NB + b) * CC + c0)) << 16) + (i << 8) + j] =
            __float2bfloat16(acc0[r]);
        qkv[(((size_t)((g1 * NB + b) * CC + c1)) << 16) + (i << 8) + j] =
            __float2bfloat16(acc1[r]);
      }
    }
  }
}

// =======================================================================
// Kernel 2a: dw(q,k) + normalize + attn = relu(tau * Q^T K) via bf16 MFMA.
// Round-8: 5 barriers (was 9); register sumsq (no atomics); per-thread scale;
// T14 prefetch of k halo under q's dw compute.
// =======================================================================
__global__ __launch_bounds__(256) void k_attn(const __hip_bfloat16* __restrict__ qkv,
                                              const float* __restrict__ wdw,
                                              const float* __restrict__ temp_p,
                                              float* __restrict__ attn_out) {
  __shared__ unsigned short halo_s[128 * 168];   // 43008 B
  __shared__ unsigned short q_t[128][72];        // [c][p] bf16 (144 B stride)
  __shared__ unsigned short k_t[128][72];
  __shared__ float sumsq_s[2][64];

  int blk = blockIdx.x;              // b*1024 + n
  int b = blk >> 10, n = blk & 1023;
  int ih0 = (n >> 5) << 3, iw0 = (n & 31) << 3;
  int t = threadIdx.x;
  int ch_l = t & 15, grp = t >> 4;
  int pr = grp & 7, contrib = grp >> 3;   // thread's 4 dw tasks share pr
  float tau = temp_p[0];
  const __hip_bfloat16* qbase = qkv + (((size_t)(b * CC)) << 16);
  const __hip_bfloat16* kbase = qkv + (((size_t)((NB + b) * CC)) << 16);

  // phase 0: q halo stage
#pragma unroll
  for (int it = 0; it < 15; ++it) {
    int idx = it * 256 + t;
    halo_store_one(halo_s, idx, halo_load_one(qbase, ih0, iw0, idx));
  }
  __syncthreads();                               // B1

  // phase 1: T14 prefetch — issue k-halo loads; hide under q's dw
  uint4 kpre[15];
#pragma unroll
  for (int it = 0; it < 15; ++it)
    kpre[it] = halo_load_one(kbase, ih0, iw0, it * 256 + t);

  // phase 2: dw q + register sumsq
  float outv[4][8];
  float ssq[8];
#pragma unroll
  for (int pc = 0; pc < 8; ++pc) ssq[pc] = 0.f;
#pragma unroll
  for (int it = 0; it < 4; ++it) {
    int ch = ((contrib + 2 * it) << 4) + ch_l;
    float wd[9];
#pragma unroll
    for (int kk = 0; kk < 9; ++kk) wd[kk] = wdw[ch * 9 + kk];
    dw_row(halo_s, wd, ch, pr, outv[it]);
#pragma unroll
    for (int pc = 0; pc < 8; ++pc) ssq[pc] = fmaf(outv[it][pc], outv[it][pc], ssq[pc]);
  }
#pragma unroll
  for (int pc = 0; pc < 8; ++pc) {
    float s = ssq[pc];
    s += __shfl_xor(s, 1);
    s += __shfl_xor(s, 2);
    s += __shfl_xor(s, 4);
    s += __shfl_xor(s, 8);
    ssq[pc] = s;                      // sum over this lane-group's 64 ch
  }
  if (ch_l == 0) {
#pragma unroll
    for (int pc = 0; pc < 8; ++pc) sumsq_s[contrib][pr * 8 + pc] = ssq[pc];
  }
  __syncthreads();                               // B2

  // phase 3: write prefetched k halo
#pragma unroll
  for (int it = 0; it < 15; ++it) halo_store_one(halo_s, it * 256 + t, kpre[it]);

  // phase 4: per-thread q scale + q_t write ([c][p])
  {
    float psv[8];
#pragma unroll
    for (int pc = 0; pc < 8; ++pc) {
      float s = sumsq_s[0][pr * 8 + pc] + sumsq_s[1][pr * 8 + pc];
      psv[pc] = 1.f / fmaxf(sqrtf(s), 1e-12f);
    }
#pragma unroll
    for (int it = 0; it < 4; ++it) {
      int ch = ((contrib + 2 * it) << 4) + ch_l;
      unsigned short o8[8];
#pragma unroll
      for (int pc = 0; pc < 8; ++pc) o8[pc] = f2bf(outv[it][pc] * psv[pc]);
      *(uint4*)&q_t[ch][pr * 8] = *(const uint4*)o8;
    }
  }
  __syncthreads();                               // B3 (k halo ready)

  // phase 5: dw k + register sumsq
#pragma unroll
  for (int pc = 0; pc < 8; ++pc) ssq[pc] = 0.f;
#pragma unroll
  for (int it = 0; it < 4; ++it) {
    int ch = ((contrib + 2 * it) << 4) + ch_l;
    float wd[9];
#pragma unroll
    for (int kk = 0; kk < 9; ++kk) wd[kk] = wdw[(CC + ch) * 9 + kk];
    dw_row(halo_s, wd, ch, pr, outv[it]);
#pragma unroll
    for (int pc = 0; pc < 8; ++pc) ssq[pc] = fmaf(outv[it][pc], outv[it][pc], ssq[pc]);
  }
#pragma unroll
  for (int pc = 0; pc < 8; ++pc) {
    float s = ssq[pc];
    s += __shfl_xor(s, 1);
    s += __shfl_xor(s, 2);
    s += __shfl_xor(s, 4);
    s += __shfl_xor(s, 8);
    ssq[pc] = s;
  }
  if (ch_l == 0) {
#pragma unroll
    for (int pc = 0; pc < 8; ++pc) sumsq_s[contrib][pr * 8 + pc] = ssq[pc];
  }
  __syncthreads();                               // B4

  // phase 6: per-thread k scale (tau folded) + k_t write
  {
    float psv[8];
#pragma unroll
    for (int pc = 0; pc < 8; ++pc) {
      float s = sumsq_s[0][pr * 8 + pc] + sumsq_s[1][pr * 8 + pc];
      psv[pc] = tau / fmaxf(sqrtf(s), 1e-12f);
    }
#pragma unroll
    for (int it = 0; it < 4; ++it) {
      int ch = ((contrib + 2 * it) << 4) + ch_l;
      unsigned short o8[8];
#pragma unroll
      for (int pc = 0; pc < 8; ++pc) o8[pc] = f2bf(outv[it][pc] * psv[pc]);
      *(uint4*)&k_t[ch][pr * 8] = *(const uint4*)o8;
    }
  }
  __syncthreads();                               // B5

  // phase 7: attn[c][d] = sum_p q_t[c][p] * k_t[d][p]
  int wv = t >> 6, lane = t & 63;
  int col = lane & 15, kg = lane >> 4;
  int c0 = wv * 32;
  bf16x8 afr[2][2];
#pragma unroll
  for (int mt = 0; mt < 2; ++mt)
#pragma unroll
    for (int ks = 0; ks < 2; ++ks)
      afr[mt][ks] = *(const bf16x8*)&q_t[c0 + mt * 16 + col][ks * 32 + kg * 8];
  float* ao = attn_out + ((size_t)blk << 14);   // 128*128 per window
#pragma unroll
  for (int dt = 0; dt < 8; ++dt) {
    bf16x8 b0 = *(const bf16x8*)&k_t[dt * 16 + col][kg * 8];
    bf16x8 b1 = *(const bf16x8*)&k_t[dt * 16 + col][32 + kg * 8];
    f32x4 a0 = {0.f, 0.f, 0.f, 0.f};
    f32x4 a1 = {0.f, 0.f, 0.f, 0.f};
    a0 = __builtin_amdgcn_mfma_f32_16x16x32_bf16(afr[0][0], b0, a0, 0, 0, 0);
    a0 = __builtin_amdgcn_mfma_f32_16x16x32_bf16(afr[0][1], b1, a0, 0, 0, 0);
    a1 = __builtin_amdgcn_mfma_f32_16x16x32_bf16(afr[1][0], b0, a1, 0, 0, 0);
    a1 = __builtin_amdgcn_mfma_f32_16x16x32_bf16(afr[1][1], b1, a1, 0, 0, 0);
#pragma unroll
    for (int r = 0; r < 4; ++r) {
      ao[((c0 + kg * 4 + r) << 7) + dt * 16 + col] = fmaxf(a0[r], 0.f);
      ao[((c0 + 16 + kg * 4 + r) << 7) + dt * 16 + col] = fmaxf(a1[r], 0.f);
    }
  }
}

// a_t swizzled byte address: stride 272 B/row; XOR of byte bits 4-6 with
// (d>>2)&7 spreads the d-striding transpose writes across 8 bank groups
// (16-way -> ~4-way). Injective (rows with equal swizzle are >=4*272 B apart).
__device__ __forceinline__ int at_addr(int d, int cbyte) {
  int a = d * 272 + cbyte;
  return a ^ (((d >> 2) & 7) << 4);
}

// =======================================================================
// Kernel 2b: dw(v) + out = V * attn via bf16 MFMA.
// Round-8: 3 barriers (was 9); T14 prefetch of attn (coalesced float4);
// one-shot a_t transpose into dead halo buffer, XOR-swizzled.
// LDS 60.5 KB -> 2 blocks/CU.
// =======================================================================
__global__ __launch_bounds__(256) void k_pv(const __hip_bfloat16* __restrict__ qkv,
                                            const float* __restrict__ wdw,
                                            const float* __restrict__ attn,
                                            __hip_bfloat16* __restrict__ out_win) {
  __shared__ unsigned short halo_s[128 * 168];   // aliased by a_t after dw
  __shared__ unsigned short v_t[64][136];        // [p][c] bf16

  int blk = blockIdx.x;
  int b = blk >> 10, n = blk & 1023;
  int ih0 = (n >> 5) << 3, iw0 = (n & 31) << 3;
  int t = threadIdx.x;
  int ch_l = t & 15, grp = t >> 4;
  int pr = grp & 7, contrib = grp >> 3;
  const __hip_bfloat16* vbase = qkv + (((size_t)((2 * NB + b) * CC)) << 16);

  // phase 0: v halo stage
#pragma unroll
  for (int it = 0; it < 15; ++it) {
    int idx = it * 256 + t;
    halo_store_one(halo_s, idx, halo_load_one(vbase, ih0, iw0, idx));
  }
  __syncthreads();                               // B1

  // phase 1: T14 prefetch attn rows (coalesced 512 B per half-wave)
  const float* ab = attn + ((size_t)blk << 14);
  float4 apre[8][2];
#pragma unroll
  for (int it = 0; it < 8; ++it) {
    int idx = it * 256 + t;
    int d4 = idx & 31, cp = idx >> 5;            // c-pair 0..63, d-quad 0..31
    const float* ar = ab + ((2 * cp) << 7) + 4 * d4;
    apre[it][0] = *(const float4*)ar;
    apre[it][1] = *(const float4*)(ar + 128);
  }

  // phase 2: dw v -> v_t [p][c]
#pragma unroll
  for (int it = 0; it < 4; ++it) {
    int ch = ((contrib + 2 * it) << 4) + ch_l;
    float wd[9];
#pragma unroll
    for (int kk = 0; kk < 9; ++kk) wd[kk] = wdw[(2 * CC + ch) * 9 + kk];
    float outv[8];
    dw_row(halo_s, wd, ch, pr, outv);
#pragma unroll
    for (int pc = 0; pc < 8; ++pc) v_t[pr * 8 + pc][ch] = f2bf(outv[pc]);
  }
  __syncthreads();                               // B2 (halo dead, v_t ready)

  // phase 3: a_t transpose write (over halo_s), swizzled
  unsigned short* a_t = halo_s;
#pragma unroll
  for (int it = 0; it < 8; ++it) {
    int idx = it * 256 + t;
    int d4 = idx & 31, cp = idx >> 5;
    float lo[4], hi[4];
    *(float4*)lo = apre[it][0];
    *(float4*)hi = apre[it][1];
#pragma unroll
    for (int e = 0; e < 4; ++e) {
      unsigned pk = (unsigned)f2bf(lo[e]) | ((unsigned)f2bf(hi[e]) << 16);
      *(unsigned*)((char*)a_t + at_addr(4 * d4 + e, 4 * cp)) = pk;
    }
  }
  __syncthreads();                               // B3

  // phase 4: out[p][d] = sum_c v[p][c] * attn[c][d]
  int wv = t >> 6, lane = t & 63;
  int col = lane & 15, kg = lane >> 4;
  f32x4 acc[8];
#pragma unroll
  for (int dt = 0; dt < 8; ++dt) acc[dt] = {0.f, 0.f, 0.f, 0.f};
#pragma unroll
  for (int ks = 0; ks < 4; ++ks) {
    bf16x8 va = *(const bf16x8*)&v_t[wv * 16 + col][ks * 32 + kg * 8];
#pragma unroll
    for (int dt = 0; dt < 8; ++dt) {
      bf16x8 bf = *(const bf16x8*)((const char*)a_t +
                                   at_addr(dt * 16 + col, (ks * 32 + kg * 8) * 2));
      acc[dt] = __builtin_amdgcn_mfma_f32_16x16x32_bf16(va, bf, acc[dt], 0, 0, 0);
    }
  }
  __hip_bfloat16* ow = out_win + ((size_t)blk << 13);   // 64*128 per window
#pragma unroll
  for (int dt = 0; dt < 8; ++dt)
#pragma unroll
    for (int r = 0; r < 4; ++r)
      ow[((wv * 16 + kg * 4 + r) << 7) + dt * 16 + col] = __float2bfloat16(acc[dt][r]);
}

// =======================================================================
// Kernel 3: proj 1x1 as bf16 MFMA GEMM (unchanged, verified).
// =======================================================================
__global__ __launch_bounds__(256) void k_proj_mfma(const __hip_bfloat16* __restrict__ out_win,
                                                   const float* __restrict__ wp,
                                                   float* __restrict__ y) {
  __shared__ unsigned short w_s[128 * 136];   // [och][c] bf16

  int t = threadIdx.x;
  {
    int och = t >> 1, ch0 = (t & 1) << 6;
    const float* wr = wp + och * CC + ch0;
#pragma unroll
    for (int u = 0; u < 32; ++u) {
      float2 v = *(const float2*)(wr + 2 * u);
      unsigned pk = (unsigned)f2bf(v.x) | ((unsigned)f2bf(v.y) << 16);
      *(unsigned*)&w_s[och * 136 + ch0 + 2 * u] = pk;
    }
  }
  __syncthreads();

  int w = t >> 6, lane = t & 63;
  int col = lane & 15, kg = lane >> 4;
  int bn = blockIdx.x * 4 + w;
  int b = bn >> 10, n = bn & 1023;
  const __hip_bfloat16* ob = out_win + ((size_t)bn << 13);

  bf16x8 afr[8][4];
#pragma unroll
  for (int mt = 0; mt < 8; ++mt)
#pragma unroll
    for (int ks = 0; ks < 4; ++ks)
      afr[mt][ks] = *(const bf16x8*)&w_s[(mt * 16 + col) * 136 + ks * 32 + kg * 8];

#pragma unroll 1
  for (int nt = 0; nt < 4; ++nt) {
    int p = nt * 16 + col;
    bf16x8 bfr[4];
#pragma unroll
    for (int ks = 0; ks < 4; ++ks)
      bfr[ks] = *(const bf16x8*)(ob + p * CC + ks * 32 + kg * 8);
    int i_f = (((n >> 5) << 3) + (p >> 3) + 4) & 255;
    int j_f = (((n & 31) << 3) + (p & 7) + 4) & 255;
    float* yp = y + (((size_t)b * CC) << 16) + (i_f << 8) + j_f;
#pragma unroll
    for (int mt = 0; mt < 8; ++mt) {
      f32x4 acc = {0.f, 0.f, 0.f, 0.f};
#pragma unroll
      for (int ks = 0; ks < 4; ++ks)
        acc = __builtin_amdgcn_mfma_f32_16x16x32_bf16(afr[mt][ks], bfr[ks], acc, 0, 0, 0);
#pragma unroll
      for (int r = 0; r < 4; ++r) {
        int och = mt * 16 + kg * 4 + r;
        yp[(size_t)och << 16] = acc[r];
      }
    }
  }
}

extern "C" void kernel_launch(void* const* d_in, const int* in_sizes, int n_in,
                              void* d_out, int out_size, void* d_ws, size_t ws_size,
                              hipStream_t stream) {
  const float* x = (const float*)d_in[0];
  const float* w_qkv = (const float*)d_in[1];
  const float* w_dw = (const float*)d_in[2];
  const float* w_proj = (const float*)d_in[3];
  const float* temp = (const float*)d_in[4];
  float* y = (float*)d_out;
  float* attn = (float*)d_out + (size_t)NB * CC * HW;   // y first, then attn

  // d_ws (bf16): qkv [3][b][c][hw] = 201 MB; out_win (67 MB) reuses the q
  // region (dead after k_attn; disjoint from v region read by k_pv).
  __hip_bfloat16* qkv = (__hip_bfloat16*)d_ws;
  __hip_bfloat16* out_win = (__hip_bfloat16*)d_ws;

  k_qkv_mfma<<<2048, 256, 0, stream>>>(x, w_qkv, qkv);
  k_attn<<<4096, 256, 0, stream>>>(qkv, w_dw, temp, attn);
  k_pv<<<4096, 256, 0, stream>>>(qkv, w_dw, attn, out_win);
  k_proj_mfma<<<1024, 256, 0, stream>>>(out_win, w_proj, y);
}

// Round 9
// 646.588 us; speedup vs baseline: 12.7073x; 1.0467x over previous
//
#include <hip/hip_runtime.h>
#include <hip/hip_bf16.h>

// Problem constants
constexpr int NB = 4;        // batch
constexpr int CC = 128;      // channels
constexpr int HW = 65536;    // 256*256 pixels per (b, channel) plane
// windows: 32x32 = 1024 per batch, 8x8 = 64 px per window

using bf16x8 = __attribute__((ext_vector_type(8))) short;   // MFMA A/B frag (4 VGPR)
using f32x4  = __attribute__((ext_vector_type(4))) float;   // MFMA C/D frag

__device__ __forceinline__ unsigned short f2bf(float f) {
  unsigned u = __builtin_bit_cast(unsigned, f);
  u += 0x7FFFu + ((u >> 16) & 1u);
  return (unsigned short)(u >> 16);
}
__device__ __forceinline__ float bf2f(unsigned short s) {
  return __builtin_bit_cast(float, (unsigned)s << 16);
}

// Halo LDS layout: halo[ch*168 + r*16 + slot], r = 0..9 (image row ih0-1+r).
// slot 0..7 = window px, slot 8 = right halo, 9 = left halo. ch stride 336 B.
__device__ __forceinline__ void halo_decomp(int idx, int& ch, int& r, int& c) {
  ch = idx / 30;
  int rem = idx - ch * 30;
  r = rem / 3;
  c = rem - r * 3;
}
__device__ __forceinline__ uint4 halo_load_one(const __hip_bfloat16* __restrict__ base,
                                               int ih0, int iw0, int idx) {
  int ch, r, c;
  halo_decomp(idx, ch, r, c);
  int ii = ih0 - 1 + r, j0 = iw0 - 8 + c * 8;
  uint4 v = {0u, 0u, 0u, 0u};
  if ((unsigned)ii < 256u && (unsigned)j0 <= 248u)
    v = *(const uint4*)(base + (((size_t)ch) << 16) + (ii << 8) + j0);
  return v;
}
__device__ __forceinline__ void halo_store_one(unsigned short* __restrict__ halo,
                                               int idx, uint4 v) {
  int ch, r, c;
  halo_decomp(idx, ch, r, c);
  unsigned short* hrow = halo + ch * 168 + r * 16;
  if (c == 1) *(uint4*)hrow = v;
  else if (c == 0) hrow[9] = (unsigned short)(v.w >> 16);
  else hrow[8] = (unsigned short)(v.x & 0xFFFFu);
}

// dw 3x3 for one (ch, pr) output row of 8 px.
__device__ __forceinline__ void dw_row(const unsigned short* __restrict__ halo,
                                       const float* __restrict__ wd,
                                       int ch, int pr, float* __restrict__ outv) {
#pragma unroll
  for (int pc = 0; pc < 8; ++pc) outv[pc] = 0.f;
#pragma unroll
  for (int kr = 0; kr < 3; ++kr) {
    const unsigned short* hrow = halo + ch * 168 + (pr + kr) * 16;
    uint4 rw = *(const uint4*)hrow;
    float rv[10];
    rv[0] = bf2f((unsigned short)(rw.x & 0xFFFFu));
    rv[1] = bf2f((unsigned short)(rw.x >> 16));
    rv[2] = bf2f((unsigned short)(rw.y & 0xFFFFu));
    rv[3] = bf2f((unsigned short)(rw.y >> 16));
    rv[4] = bf2f((unsigned short)(rw.z & 0xFFFFu));
    rv[5] = bf2f((unsigned short)(rw.z >> 16));
    rv[6] = bf2f((unsigned short)(rw.w & 0xFFFFu));
    rv[7] = bf2f((unsigned short)(rw.w >> 16));
    rv[8] = bf2f(hrow[8]);   // right
    rv[9] = bf2f(hrow[9]);   // left
#pragma unroll
    for (int s = 0; s < 3; ++s) {
      float wv = wd[kr * 3 + s];
#pragma unroll
      for (int pc = 0; pc < 8; ++pc) {
        int m = pc + s - 1;
        float xv = (m < 0) ? rv[9] : rv[m];
        outv[pc] = fmaf(wv, xv, outv[pc]);
      }
    }
  }
}

// =======================================================================
// Kernel 1: rolled 1x1 conv as bf16 MFMA GEMM (unchanged, verified).
// =======================================================================
__global__ __launch_bounds__(256) void k_qkv_mfma(const float* __restrict__ x,
                                                  const float* __restrict__ wq,
                                                  __hip_bfloat16* __restrict__ qkv) {
  __shared__ unsigned short x_s[128 * 136];   // [px][c]

  int blk = blockIdx.x;                 // 4 b x 256 i x 2 j-half
  int b = blk >> 9, i = (blk >> 1) & 255, jh = blk & 1;
  int j0 = jh << 7;
  int si = (i + 4) & 255;               // roll(-4): source row
  int t = threadIdx.x;

  {
    int c0 = (t & 63) << 1;
    int jb = (t >> 6) << 5;
    const float* xr0 = x + (((size_t)(b * CC + c0)) << 16) + (si << 8);
    const float* xr1 = xr0 + HW;
#pragma unroll
    for (int u = 0; u < 8; ++u) {
      int jj = jb + (u << 2);
      int sj = j0 + jj + 4;
      float v0[4], v1[4];
      if (sj + 3 <= 255) {
        *(float4*)v0 = *(const float4*)(xr0 + sj);
        *(float4*)v1 = *(const float4*)(xr1 + sj);
      } else {
#pragma unroll
        for (int e = 0; e < 4; ++e) {
          int s = (sj + e) & 255;
          v0[e] = xr0[s];
          v1[e] = xr1[s];
        }
      }
#pragma unroll
      for (int e = 0; e < 4; ++e) {
        unsigned pk = (unsigned)f2bf(v0[e]) | ((unsigned)f2bf(v1[e]) << 16);
        *(unsigned*)&x_s[(jj + e) * 136 + c0] = pk;
      }
    }
  }
  __syncthreads();

  int w = t >> 6;
  int lane = t & 63;
  int col = lane & 15;
  int kg = lane >> 4;

#pragma unroll 1
  for (int oi = 0; oi < 3; ++oi) {
    int m0 = oi * 128 + w * 32;
    bf16x8 afr[2][4];
#pragma unroll
    for (int mt = 0; mt < 2; ++mt) {
      const float* wr = wq + (m0 + mt * 16 + col) * CC + kg * 8;
#pragma unroll
      for (int ks = 0; ks < 4; ++ks) {
        float wa[4], wb[4];
        *(float4*)wa = *(const float4*)(wr + ks * 32);
        *(float4*)wb = *(const float4*)(wr + ks * 32 + 4);
        bf16x8 f;
#pragma unroll
        for (int e = 0; e < 4; ++e) {
          f[e] = (short)f2bf(wa[e]);
          f[e + 4] = (short)f2bf(wb[e]);
        }
        afr[mt][ks] = f;
      }
    }
#pragma unroll 1
    for (int n = 0; n < 8; ++n) {
      int px = n * 16 + col;
      f32x4 acc0 = {0.f, 0.f, 0.f, 0.f};
      f32x4 acc1 = {0.f, 0.f, 0.f, 0.f};
#pragma unroll
      for (int ks = 0; ks < 4; ++ks) {
        bf16x8 bfr = *(const bf16x8*)&x_s[px * 136 + ks * 32 + kg * 8];
        acc0 = __builtin_amdgcn_mfma_f32_16x16x32_bf16(afr[0][ks], bfr, acc0, 0, 0, 0);
        acc1 = __builtin_amdgcn_mfma_f32_16x16x32_bf16(afr[1][ks], bfr, acc1, 0, 0, 0);
      }
      int j = j0 + n * 16 + col;
#pragma unroll
      for (int r = 0; r < 4; ++r) {
        int och0 = m0 + kg * 4 + r;
        int och1 = m0 + 16 + kg * 4 + r;
        int g0 = och0 >> 7, c0 = och0 & 127;
        int g1 = och1 >> 7, c1 = och1 & 127;
        qkv[(((size_t)((g0 * NB + b) * CC + c0)) << 16) + (i << 8) + j] =
            __float2bfloat16(acc0[r]);
        qkv[(((size_t)((g1 * NB + b) * CC + c1)) << 16) + (i << 8) + j] =
            __float2bfloat16(acc1[r]);
      }
    }
  }
}

// =======================================================================
// Kernel 2 (FUSED): dw(q,k,v) + normalize + attn + PV + proj, one window/block.
// Phase plan (LDS aliasing, barriers B1..B11):
//   halo_s (43008 B): q halo -> k halo -> v halo -> a_t[128][136] -> po_t[64][136]
//   q_t[128][72] (18432 B): q_t -> v_t[64][136] (17408 B)
//   k_t[128][72]: k_t only
// attn kept in 64 VGPRs between QK^T and a_t write. Wp A-frags from global
// (L2-resident, k_qkv pattern). XCD swizzle: 4096 = 8 XCDs x 512 contiguous.
// =======================================================================
__global__ __launch_bounds__(256, 2) void k_fused(const __hip_bfloat16* __restrict__ qkv,
                                                  const float* __restrict__ wdw,
                                                  const float* __restrict__ temp_p,
                                                  const float* __restrict__ wp,
                                                  float* __restrict__ attn_out,
                                                  float* __restrict__ y) {
  __shared__ unsigned short halo_s[128 * 168];   // 43008 B
  __shared__ unsigned short q_t[128][72];        // 18432 B
  __shared__ unsigned short k_t[128][72];        // 18432 B
  __shared__ float sumsq_s[2][64];

  int bid = blockIdx.x;
  int blk = ((bid & 7) << 9) + (bid >> 3);   // XCD-aware swizzle (bijective)
  int b = blk >> 10, n = blk & 1023;
  int ih0 = (n >> 5) << 3, iw0 = (n & 31) << 3;
  int t = threadIdx.x;
  int ch_l = t & 15, grp = t >> 4;
  int pr = grp & 7, contrib = grp >> 3;
  float tau = temp_p[0];
  const __hip_bfloat16* qbase = qkv + (((size_t)(b * CC)) << 16);
  const __hip_bfloat16* kbase = qkv + (((size_t)((NB + b) * CC)) << 16);
  const __hip_bfloat16* vbase = qkv + (((size_t)((2 * NB + b) * CC)) << 16);

  // ---- P0: q halo stage
#pragma unroll
  for (int it = 0; it < 15; ++it) {
    int idx = it * 256 + t;
    halo_store_one(halo_s, idx, halo_load_one(qbase, ih0, iw0, idx));
  }
  __syncthreads();                               // B1

  // ---- P1: T14 prefetch k halo; dw q + register sumsq
  uint4 kpre[15];
#pragma unroll
  for (int it = 0; it < 15; ++it)
    kpre[it] = halo_load_one(kbase, ih0, iw0, it * 256 + t);

  float outv[4][8];
  float ssq[8];
#pragma unroll
  for (int pc = 0; pc < 8; ++pc) ssq[pc] = 0.f;
#pragma unroll
  for (int it = 0; it < 4; ++it) {
    int ch = ((contrib + 2 * it) << 4) + ch_l;
    float wd[9];
#pragma unroll
    for (int kk = 0; kk < 9; ++kk) wd[kk] = wdw[ch * 9 + kk];
    dw_row(halo_s, wd, ch, pr, outv[it]);
#pragma unroll
    for (int pc = 0; pc < 8; ++pc) ssq[pc] = fmaf(outv[it][pc], outv[it][pc], ssq[pc]);
  }
#pragma unroll
  for (int pc = 0; pc < 8; ++pc) {
    float s = ssq[pc];
    s += __shfl_xor(s, 1);
    s += __shfl_xor(s, 2);
    s += __shfl_xor(s, 4);
    s += __shfl_xor(s, 8);
    ssq[pc] = s;
  }
  if (ch_l == 0) {
#pragma unroll
    for (int pc = 0; pc < 8; ++pc) sumsq_s[contrib][pr * 8 + pc] = ssq[pc];
  }
  __syncthreads();                               // B2

  // ---- P2: write k halo; q scale + q_t write
#pragma unroll
  for (int it = 0; it < 15; ++it) halo_store_one(halo_s, it * 256 + t, kpre[it]);
  {
    float psv[8];
#pragma unroll
    for (int pc = 0; pc < 8; ++pc) {
      float s = sumsq_s[0][pr * 8 + pc] + sumsq_s[1][pr * 8 + pc];
      psv[pc] = 1.f / fmaxf(sqrtf(s), 1e-12f);
    }
#pragma unroll
    for (int it = 0; it < 4; ++it) {
      int ch = ((contrib + 2 * it) << 4) + ch_l;
      unsigned short o8[8];
#pragma unroll
      for (int pc = 0; pc < 8; ++pc) o8[pc] = f2bf(outv[it][pc] * psv[pc]);
      *(uint4*)&q_t[ch][pr * 8] = *(const uint4*)o8;
    }
  }
  __syncthreads();                               // B3 (k halo + q_t ready)

  // ---- P3: dw k + register sumsq
#pragma unroll
  for (int pc = 0; pc < 8; ++pc) ssq[pc] = 0.f;
#pragma unroll
  for (int it = 0; it < 4; ++it) {
    int ch = ((contrib + 2 * it) << 4) + ch_l;
    float wd[9];
#pragma unroll
    for (int kk = 0; kk < 9; ++kk) wd[kk] = wdw[(CC + ch) * 9 + kk];
    dw_row(halo_s, wd, ch, pr, outv[it]);
#pragma unroll
    for (int pc = 0; pc < 8; ++pc) ssq[pc] = fmaf(outv[it][pc], outv[it][pc], ssq[pc]);
  }
#pragma unroll
  for (int pc = 0; pc < 8; ++pc) {
    float s = ssq[pc];
    s += __shfl_xor(s, 1);
    s += __shfl_xor(s, 2);
    s += __shfl_xor(s, 4);
    s += __shfl_xor(s, 8);
    ssq[pc] = s;
  }
  if (ch_l == 0) {
#pragma unroll
    for (int pc = 0; pc < 8; ++pc) sumsq_s[contrib][pr * 8 + pc] = ssq[pc];
  }
  __syncthreads();                               // B4

  // ---- P4: k scale (tau folded) + k_t write
  {
    float psv[8];
#pragma unroll
    for (int pc = 0; pc < 8; ++pc) {
      float s = sumsq_s[0][pr * 8 + pc] + sumsq_s[1][pr * 8 + pc];
      psv[pc] = tau / fmaxf(sqrtf(s), 1e-12f);
    }
#pragma unroll
    for (int it = 0; it < 4; ++it) {
      int ch = ((contrib + 2 * it) << 4) + ch_l;
      unsigned short o8[8];
#pragma unroll
      for (int pc = 0; pc < 8; ++pc) o8[pc] = f2bf(outv[it][pc] * psv[pc]);
      *(uint4*)&k_t[ch][pr * 8] = *(const uint4*)o8;
    }
  }
  __syncthreads();                               // B5 (k_t ready)

  // ---- P5: T14 prefetch v halo; QK^T; attn fp32 write; keep relu'd in regs
  uint4 vpre[15];
#pragma unroll
  for (int it = 0; it < 15; ++it)
    vpre[it] = halo_load_one(vbase, ih0, iw0, it * 256 + t);

  int wv = t >> 6, lane = t & 63;
  int col = lane & 15, kg = lane >> 4;
  int c0 = wv * 32;
  f32x4 pa0[8], pa1[8];
  {
    bf16x8 afr[2][2];
#pragma unroll
    for (int mt = 0; mt < 2; ++mt)
#pragma unroll
      for (int ks = 0; ks < 2; ++ks)
        afr[mt][ks] = *(const bf16x8*)&q_t[c0 + mt * 16 + col][ks * 32 + kg * 8];
    float* ao = attn_out + ((size_t)blk << 14);   // 128*128 per window
#pragma unroll
    for (int dt = 0; dt < 8; ++dt) {
      bf16x8 b0 = *(const bf16x8*)&k_t[dt * 16 + col][kg * 8];
      bf16x8 b1 = *(const bf16x8*)&k_t[dt * 16 + col][32 + kg * 8];
      f32x4 a0 = {0.f, 0.f, 0.f, 0.f};
      f32x4 a1 = {0.f, 0.f, 0.f, 0.f};
      a0 = __builtin_amdgcn_mfma_f32_16x16x32_bf16(afr[0][0], b0, a0, 0, 0, 0);
      a0 = __builtin_amdgcn_mfma_f32_16x16x32_bf16(afr[0][1], b1, a0, 0, 0, 0);
      a1 = __builtin_amdgcn_mfma_f32_16x16x32_bf16(afr[1][0], b0, a1, 0, 0, 0);
      a1 = __builtin_amdgcn_mfma_f32_16x16x32_bf16(afr[1][1], b1, a1, 0, 0, 0);
#pragma unroll
      for (int r = 0; r < 4; ++r) {
        a0[r] = fmaxf(a0[r], 0.f);
        a1[r] = fmaxf(a1[r], 0.f);
        ao[((c0 + kg * 4 + r) << 7) + dt * 16 + col] = a0[r];
        ao[((c0 + 16 + kg * 4 + r) << 7) + dt * 16 + col] = a1[r];
      }
      pa0[dt] = a0;
      pa1[dt] = a1;
    }
  }
  __syncthreads();                               // B6 (QK^T LDS reads done)

  // ---- P6: write v halo; dw v -> v_t (over dead q_t)
#pragma unroll
  for (int it = 0; it < 15; ++it) halo_store_one(halo_s, it * 256 + t, vpre[it]);
  __syncthreads();                               // B7 (v halo ready)

  unsigned short (*v_t)[136] = (unsigned short (*)[136])&q_t[0][0];  // 17408 B
#pragma unroll
  for (int it = 0; it < 4; ++it) {
    int ch = ((contrib + 2 * it) << 4) + ch_l;
    float wd[9];
#pragma unroll
    for (int kk = 0; kk < 9; ++kk) wd[kk] = wdw[(2 * CC + ch) * 9 + kk];
    float vo[8];
    dw_row(halo_s, wd, ch, pr, vo);
#pragma unroll
    for (int pc = 0; pc < 8; ++pc) v_t[pr * 8 + pc][ch] = f2bf(vo[pc]);
  }
  __syncthreads();                               // B8 (dw-v halo reads done)

  // ---- P7: a_t[d][c] bf16 from attn regs (over dead halo_s)
  unsigned short (*a_t)[136] = (unsigned short (*)[136])halo_s;      // 34816 B
#pragma unroll
  for (int dt = 0; dt < 8; ++dt)
#pragma unroll
    for (int r = 0; r < 4; ++r) {
      a_t[dt * 16 + col][c0 + kg * 4 + r] = f2bf(pa0[dt][r]);
      a_t[dt * 16 + col][c0 + 16 + kg * 4 + r] = f2bf(pa1[dt][r]);
    }
  __syncthreads();                               // B9 (a_t + v_t ready)

  // ---- P8: PV — out[p][d] = sum_c v[p][c] * attn[c][d]; wave wv: p-tile wv
  f32x4 pacc[8];
#pragma unroll
  for (int dt = 0; dt < 8; ++dt) pacc[dt] = {0.f, 0.f, 0.f, 0.f};
#pragma unroll
  for (int ks = 0; ks < 4; ++ks) {
    bf16x8 va = *(const bf16x8*)&v_t[wv * 16 + col][ks * 32 + kg * 8];
#pragma unroll
    for (int dt = 0; dt < 8; ++dt) {
      bf16x8 bf = *(const bf16x8*)&a_t[dt * 16 + col][ks * 32 + kg * 8];
      pacc[dt] = __builtin_amdgcn_mfma_f32_16x16x32_bf16(va, bf, pacc[dt], 0, 0, 0);
    }
  }
  __syncthreads();                               // B10 (PV LDS reads done)

  // ---- P9: po_t[p][d] bf16 (over dead a_t region)
  unsigned short (*po_t)[136] = (unsigned short (*)[136])halo_s;     // 17408 B
#pragma unroll
  for (int dt = 0; dt < 8; ++dt)
#pragma unroll
    for (int r = 0; r < 4; ++r)
      po_t[wv * 16 + kg * 4 + r][dt * 16 + col] = f2bf(pacc[dt][r]);
  __syncthreads();                               // B11 (po_t ready)

  // ---- P10: proj — y[och][px] = sum_c Wp[och][c] * po[px][c]; wave wv: its 16 px
  {
    int p = wv * 16 + col;
    bf16x8 bfr[4];
#pragma unroll
    for (int ks = 0; ks < 4; ++ks)
      bfr[ks] = *(const bf16x8*)&po_t[p][ks * 32 + kg * 8];
    int i_f = (((n >> 5) << 3) + (p >> 3) + 4) & 255;
    int j_f = (((n & 31) << 3) + (p & 7) + 4) & 255;
    float* yp = y + (((size_t)b * CC) << 16) + (i_f << 8) + j_f;
#pragma unroll
    for (int mt = 0; mt < 8; ++mt) {
      bf16x8 afr[4];
      const float* wr = wp + (mt * 16 + col) * CC + kg * 8;
#pragma unroll
      for (int ks = 0; ks < 4; ++ks) {
        float wa[4], wb[4];
        *(float4*)wa = *(const float4*)(wr + ks * 32);
        *(float4*)wb = *(const float4*)(wr + ks * 32 + 4);
        bf16x8 f;
#pragma unroll
        for (int e = 0; e < 4; ++e) {
          f[e] = (short)f2bf(wa[e]);
          f[e + 4] = (short)f2bf(wb[e]);
        }
        afr[ks] = f;
      }
      f32x4 acc = {0.f, 0.f, 0.f, 0.f};
#pragma unroll
      for (int ks = 0; ks < 4; ++ks)
        acc = __builtin_amdgcn_mfma_f32_16x16x32_bf16(afr[ks], bfr[ks], acc, 0, 0, 0);
#pragma unroll
      for (int r = 0; r < 4; ++r) {
        int och = mt * 16 + kg * 4 + r;
        yp[(size_t)och << 16] = acc[r];
      }
    }
  }
}

extern "C" void kernel_launch(void* const* d_in, const int* in_sizes, int n_in,
                              void* d_out, int out_size, void* d_ws, size_t ws_size,
                              hipStream_t stream) {
  const float* x = (const float*)d_in[0];
  const float* w_qkv = (const float*)d_in[1];
  const float* w_dw = (const float*)d_in[2];
  const float* w_proj = (const float*)d_in[3];
  const float* temp = (const float*)d_in[4];
  float* y = (float*)d_out;
  float* attn = (float*)d_out + (size_t)NB * CC * HW;   // y first, then attn

  // d_ws (bf16): qkv [3][b][c][hw] = 201 MB (out_win eliminated by fusion).
  __hip_bfloat16* qkv = (__hip_bfloat16*)d_ws;

  k_qkv_mfma<<<2048, 256, 0, stream>>>(x, w_qkv, qkv);
  k_fused<<<4096, 256, 0, stream>>>(qkv, w_dw, temp, w_proj, attn, y);
}